// Round 4
// baseline (782.981 us; speedup 1.0000x reference)
//
#include <hip/hip_runtime.h>
#include <math.h>
#include <stdint.h>

#define B 8
#define N 4096
#define C 64
#define D 64
#define K 16

typedef __attribute__((ext_vector_type(8))) short short8;
typedef __attribute__((ext_vector_type(4))) float f32x4;

// ---------------------------------------------------------------------------
// bf16 helpers
// ---------------------------------------------------------------------------
__device__ __forceinline__ unsigned short f2bf(float x) {
    unsigned u = __float_as_uint(x);
    unsigned r = (u + 0x7FFFu + ((u >> 16) & 1u)) >> 16;   // RNE
    return (unsigned short)r;
}
__device__ __forceinline__ float bf2f(unsigned short h) {
    return __uint_as_float(((unsigned)h) << 16);
}

// ---------------------------------------------------------------------------
// Kernel 0: per-row sqnorm (round-1 arithmetic, passed) + 3-term bf16 split
// ---------------------------------------------------------------------------
__global__ __launch_bounds__(256)
void prep_kernel(const float* __restrict__ F, float* __restrict__ sq,
                 unsigned short* __restrict__ HP, unsigned short* __restrict__ MP,
                 unsigned short* __restrict__ LP) {
    const int row = blockIdx.x * 256 + threadIdx.x;
    const float4* src = (const float4*)(F + (size_t)row * C);
    float4 v[16];
    #pragma unroll
    for (int q = 0; q < 16; q++) v[q] = src[q];

    {
        float r[8];
        #pragma unroll
        for (int j = 0; j < 8; j++) {
            float t = ((const float*)v)[j];
            r[j] = t * t;
        }
        #pragma unroll
        for (int m = 1; m < 8; m++) {
            #pragma unroll
            for (int j = 0; j < 8; j++) {
                float t = ((const float*)v)[8 * m + j];
                r[j] = fmaf(t, t, r[j]);
            }
        }
        sq[row] = ((r[0] + r[1]) + (r[2] + r[3])) + ((r[4] + r[5]) + (r[6] + r[7]));
    }

    uint4* dh = (uint4*)(HP + (size_t)row * C);
    uint4* dm = (uint4*)(MP + (size_t)row * C);
    uint4* dl = (uint4*)(LP + (size_t)row * C);
    #pragma unroll
    for (int c8 = 0; c8 < 8; c8++) {           // 8 values per chunk
        unsigned hq[4], mq[4], lq[4];
        #pragma unroll
        for (int e = 0; e < 4; e++) {
            float x0 = ((const float*)v)[c8 * 8 + 2 * e];
            float x1 = ((const float*)v)[c8 * 8 + 2 * e + 1];
            unsigned short h0 = f2bf(x0), h1 = f2bf(x1);
            float r10 = x0 - bf2f(h0), r11 = x1 - bf2f(h1);
            unsigned short m0 = f2bf(r10), m1 = f2bf(r11);
            float r20 = r10 - bf2f(m0), r21 = r11 - bf2f(m1);
            unsigned short l0 = f2bf(r20), l1 = f2bf(r21);
            hq[e] = (unsigned)h0 | ((unsigned)h1 << 16);
            mq[e] = (unsigned)m0 | ((unsigned)m1 << 16);
            lq[e] = (unsigned)l0 | ((unsigned)l1 << 16);
        }
        dh[c8] = make_uint4(hq[0], hq[1], hq[2], hq[3]);
        dm[c8] = make_uint4(mq[0], mq[1], mq[2], mq[3]);
        dl[c8] = make_uint4(lq[0], lq[1], lq[2], lq[3]);
    }
}

// ---------------------------------------------------------------------------
// Kernel 1: MFMA KNN. Block = 64 queries, 512 threads = 8 waves.
// Wave w: query-group (w&3) [16 queries], candidate-parity group g=(w>>2).
// Group g scans tiles t = 2*it + g into its own 24KB LDS region.
// Per lane: 1 query x 16 cands/tile, u64-key sorted top-16 (round-3 proven).
// Final: 8 sorted lists/query merged via 2-stage tournament.
// ---------------------------------------------------------------------------
__global__ __launch_bounds__(512, 4)
void knn_mfma_kernel(const unsigned short* __restrict__ HP,
                     const unsigned short* __restrict__ MP,
                     const unsigned short* __restrict__ LP,
                     const float* __restrict__ sqg, int* __restrict__ knn) {
    __shared__ __align__(16) char lds[65536];

    const int b  = blockIdx.y;
    const int i0 = blockIdx.x * 64;
    const unsigned short* Hb = HP + (size_t)b * N * C;
    const unsigned short* Mb = MP + (size_t)b * N * C;
    const unsigned short* Lb = LP + (size_t)b * N * C;
    const float* sqb = sqg + (size_t)b * N;

    const int tid = threadIdx.x;
    const int l   = tid & 63;
    const int w   = tid >> 6;        // 0..7
    const int qg  = w & 3;           // query group (16 queries)
    const int g   = tid >> 8;        // candidate-parity group (== w>>2)

    // ---- stage Q planes into lds[0..24576) (all 512 threads) ----
    #pragma unroll
    for (int i = 0; i < 3; i++) {
        int c     = tid + 512 * i;                 // 0..1535
        int plane = c >> 9;
        int row   = (c >> 3) & 63;
        int off   = (c & 7) * 16;                  // byte offset in row
        const unsigned short* src =
            (plane == 0 ? Hb : plane == 1 ? Mb : Lb) + (size_t)(i0 + row) * C + off / 2;
        uint4 v = *(const uint4*)src;
        *(uint4*)(lds + plane * 8192 + ((row * 128 + off) ^ ((row & 7) << 4))) = v;
    }
    __syncthreads();

    // ---- B fragments (query), register-resident ----
    const int koff = (l >> 4) * 16;
    const int swzR = (l & 7) << 4;
    const int qrow = qg * 16 + (l & 15);
    const int qb0 = (qrow * 128 + koff) ^ swzR;
    const int qb1 = (qrow * 128 + 64 + koff) ^ swzR;
    short8 bh0 = *(const short8*)(lds + qb0),         bh1 = *(const short8*)(lds + qb1);
    short8 bm0 = *(const short8*)(lds + 8192 + qb0),  bm1 = *(const short8*)(lds + 8192 + qb1);
    short8 bl0 = *(const short8*)(lds + 16384 + qb0), bl1 = *(const short8*)(lds + 16384 + qb1);

    const float sqq   = sqb[i0 + qrow];
    const int   qglob = i0 + qrow;
    const int   crow0 = (l >> 4) * 4;

    // group LDS region for candidate tiles
    char* Ch = lds + g * 24576;
    char* Cm = Ch + 8192;
    char* Cl = Ch + 16384;

    // staging geometry within group (256 threads each)
    const int gt  = tid & 255;
    const int lr  = gt >> 2;
    const int lq  = gt & 3;
    const int swzW = (lr & 7) << 4;
    const int wb0 = (lr * 128 + lq * 32) ^ swzW;
    const int wb1 = (lr * 128 + lq * 32 + 16) ^ swzW;

    uint64_t bd[16];
    #pragma unroll
    for (int k = 0; k < 16; k++) bd[k] = ~0ull;

    // prefetch first tile of this group (tile index g)
    uint4 ph0, ph1, pm0, pm1, pl0, pl1;
    {
        const size_t rb = (size_t)(g * 64 + lr) * C + lq * 16;
        const uint4* sh = (const uint4*)(Hb + rb);
        const uint4* sm = (const uint4*)(Mb + rb);
        const uint4* sl = (const uint4*)(Lb + rb);
        ph0 = sh[0]; ph1 = sh[1]; pm0 = sm[0]; pm1 = sm[1]; pl0 = sl[0]; pl1 = sl[1];
    }

    for (int it = 0; it < 32; it++) {
        const int j0 = (2 * it + g) * 64;
        __syncthreads();                        // prior tile's frag reads done
        *(uint4*)(Ch + wb0) = ph0; *(uint4*)(Ch + wb1) = ph1;
        *(uint4*)(Cm + wb0) = pm0; *(uint4*)(Cm + wb1) = pm1;
        *(uint4*)(Cl + wb0) = pl0; *(uint4*)(Cl + wb1) = pl1;
        if (it < 31) {
            const size_t rb = (size_t)(j0 + 128 + lr) * C + lq * 16;
            const uint4* sh = (const uint4*)(Hb + rb);
            const uint4* sm = (const uint4*)(Mb + rb);
            const uint4* sl = (const uint4*)(Lb + rb);
            ph0 = sh[0]; ph1 = sh[1]; pm0 = sm[0]; pm1 = sm[1]; pl0 = sl[0]; pl1 = sl[1];
        }
        __syncthreads();

        float4 sqm0 = *(const float4*)(sqb + j0 +      crow0);
        float4 sqm1 = *(const float4*)(sqb + j0 + 16 + crow0);
        float4 sqm2 = *(const float4*)(sqb + j0 + 32 + crow0);
        float4 sqm3 = *(const float4*)(sqb + j0 + 48 + crow0);

        #pragma unroll
        for (int m = 0; m < 4; m++) {
            const int arow = m * 16 + (l & 15);
            const int ab0 = (arow * 128 + koff) ^ swzR;
            const int ab1 = (arow * 128 + 64 + koff) ^ swzR;
            short8 ah0 = *(const short8*)(Ch + ab0), ah1 = *(const short8*)(Ch + ab1);
            short8 am0 = *(const short8*)(Cm + ab0), am1 = *(const short8*)(Cm + ab1);
            short8 al0 = *(const short8*)(Cl + ab0), al1 = *(const short8*)(Cl + ab1);

            f32x4 accc = {0.f, 0.f, 0.f, 0.f};          // correction terms
            accc = __builtin_amdgcn_mfma_f32_16x16x32_bf16(am0, bm0, accc, 0, 0, 0);
            accc = __builtin_amdgcn_mfma_f32_16x16x32_bf16(am1, bm1, accc, 0, 0, 0);
            accc = __builtin_amdgcn_mfma_f32_16x16x32_bf16(ah0, bl0, accc, 0, 0, 0);
            accc = __builtin_amdgcn_mfma_f32_16x16x32_bf16(ah1, bl1, accc, 0, 0, 0);
            accc = __builtin_amdgcn_mfma_f32_16x16x32_bf16(al0, bh0, accc, 0, 0, 0);
            accc = __builtin_amdgcn_mfma_f32_16x16x32_bf16(al1, bh1, accc, 0, 0, 0);
            accc = __builtin_amdgcn_mfma_f32_16x16x32_bf16(ah0, bm0, accc, 0, 0, 0);
            accc = __builtin_amdgcn_mfma_f32_16x16x32_bf16(ah1, bm1, accc, 0, 0, 0);
            accc = __builtin_amdgcn_mfma_f32_16x16x32_bf16(am0, bh0, accc, 0, 0, 0);
            accc = __builtin_amdgcn_mfma_f32_16x16x32_bf16(am1, bh1, accc, 0, 0, 0);
            f32x4 acch = {0.f, 0.f, 0.f, 0.f};          // hi*hi (dominant)
            acch = __builtin_amdgcn_mfma_f32_16x16x32_bf16(ah0, bh0, acch, 0, 0, 0);
            acch = __builtin_amdgcn_mfma_f32_16x16x32_bf16(ah1, bh1, acch, 0, 0, 0);

            float4 sqm = (m == 0) ? sqm0 : (m == 1) ? sqm1 : (m == 2) ? sqm2 : sqm3;
            #pragma unroll
            for (int r = 0; r < 4; r++) {
                const int cg = j0 + m * 16 + crow0 + r;
                float sqc = (r == 0) ? sqm.x : (r == 1) ? sqm.y : (r == 2) ? sqm.z : sqm.w;
                float gg = acch[r] + accc[r];
                float d2 = fmaf(-2.0f, gg, sqq + sqc);
                if (cg == qglob) d2 = INFINITY;
                d2 = fmaxf(d2, 0.0f);
                uint64_t key = ((uint64_t)__float_as_uint(d2) << 32) | (unsigned)cg;
                if (key < bd[15]) {
                    bool c[16];
                    #pragma unroll
                    for (int k = 0; k < 16; k++) c[k] = key < bd[k];
                    #pragma unroll
                    for (int k = 15; k >= 1; --k)
                        bd[k] = c[k - 1] ? bd[k - 1] : (c[k] ? key : bd[k]);
                    bd[0] = c[0] ? key : bd[0];
                }
            }
        }
    }

    // ---- dump 8 sorted lists per query ----
    __syncthreads();
    uint64_t* keys = (uint64_t*)lds;           // 64 q x 8 lists x 16 x 8B = 64KB
    {
        const int qloc = qg * 16 + (l & 15);
        const int lid  = g * 4 + (l >> 4);
        const int base = (qloc * 8 + lid) * 16;
        #pragma unroll
        for (int k = 0; k < 16; k++) keys[base + k] = bd[k];
    }
    __syncthreads();

    // ---- stage 1: 128 threads, each 4-way merges half a query's lists ----
    uint64_t s1[16];
    const int q1 = tid >> 1, h1v = tid & 1;
    if (tid < 128) {
        const uint64_t* L0 = keys + (q1 * 8 + h1v * 4) * 16;
        const uint64_t* L1 = L0 + 16;
        const uint64_t* L2 = L0 + 32;
        const uint64_t* L3 = L0 + 48;
        int p0 = 0, p1 = 0, p2 = 0, p3 = 0;
        uint64_t h0 = L0[0], h1 = L1[0], h2 = L2[0], h3 = L3[0];
        #pragma unroll
        for (int k = 0; k < 16; k++) {
            uint64_t m01 = h0 < h1 ? h0 : h1;
            uint64_t m23 = h2 < h3 ? h2 : h3;
            uint64_t mv  = m01 < m23 ? m01 : m23;
            s1[k] = mv;
            if      (mv == h0) { ++p0; h0 = (p0 < 16) ? L0[p0] : ~0ull; }
            else if (mv == h1) { ++p1; h1 = (p1 < 16) ? L1[p1] : ~0ull; }
            else if (mv == h2) { ++p2; h2 = (p2 < 16) ? L2[p2] : ~0ull; }
            else               { ++p3; h3 = (p3 < 16) ? L3[p3] : ~0ull; }
        }
    }
    __syncthreads();
    if (tid < 128) {
        #pragma unroll
        for (int k = 0; k < 16; k++) keys[(q1 * 2 + h1v) * 16 + k] = s1[k];
    }
    __syncthreads();

    // ---- stage 2: 64 threads, 2-way merge -> final 16 indices ----
    if (tid < 64) {
        const uint64_t* A = keys + (tid * 2) * 16;
        const uint64_t* Bp = A + 16;
        int pa = 0, pb = 0;
        uint64_t ha = A[0], hb = Bp[0];
        int* dst = knn + ((size_t)b * N + i0 + tid) * K;
        #pragma unroll
        for (int k = 0; k < K; k++) {
            uint64_t mv = ha < hb ? ha : hb;
            dst[k] = (int)(mv & 0xFFFFFFFFu);
            if (mv == ha) { ++pa; ha = (pa < 16) ? A[pa] : ~0ull; }
            else          { ++pb; hb = (pb < 16) ? Bp[pb] : ~0ull; }
        }
    }
}

// ---------------------------------------------------------------------------
// Kernel 2: gather + 2-layer MLP + max over K (unchanged — passed round 1)
// ---------------------------------------------------------------------------
__device__ __forceinline__ float gelu_exact(float x) {
    return 0.5f * x * (1.0f + erff(x * 0.70710678118654752440f));
}

__global__ __launch_bounds__(256)
void edgeconv_mlp_kernel(const float* __restrict__ F, const int* __restrict__ knn,
                         const float* __restrict__ W1, const float* __restrict__ b1,
                         const float* __restrict__ W2, const float* __restrict__ b2,
                         float* __restrict__ out) {
    __shared__ float4 nd4[4][K][16];
    __shared__ float4 h14[4][K][16];
    __shared__ float  cs[4][64];

    const int tid = threadIdx.x;
    const int w   = tid >> 6;
    const int t   = tid & 63;
    const int qi  = blockIdx.x * 4 + w;
    const int b   = qi >> 12;
    const int i   = qi & (N - 1);
    const float* Fb = F + (size_t)b * N * C;

    float ct = Fb[(size_t)i * C + t];
    cs[w][t] = ct;

    int ids[K];
    const int* kp = knn + (size_t)qi * K;
    #pragma unroll
    for (int k = 0; k < K; k++) ids[k] = kp[k];

    #pragma unroll
    for (int k = 0; k < K; k++) {
        float v = Fb[(size_t)ids[k] * C + t];
        ((float*)&nd4[w][k][0])[t] = v - ct;
    }
    __syncthreads();

    float s0a = b1[t], s0b = 0.f, s0c = 0.f, s0d = 0.f;
    for (int c = 0; c < C; c += 4) {
        s0a = fmaf(cs[w][c + 0], W1[(c + 0) * D + t], s0a);
        s0b = fmaf(cs[w][c + 1], W1[(c + 1) * D + t], s0b);
        s0c = fmaf(cs[w][c + 2], W1[(c + 2) * D + t], s0c);
        s0d = fmaf(cs[w][c + 3], W1[(c + 3) * D + t], s0d);
    }
    float s0 = (s0a + s0b) + (s0c + s0d);

    float acc[K];
    #pragma unroll
    for (int k = 0; k < K; k++) acc[k] = s0;

    for (int c4 = 0; c4 < 16; c4++) {
        float wa = W1[(C + c4 * 4 + 0) * D + t];
        float wb = W1[(C + c4 * 4 + 1) * D + t];
        float wc = W1[(C + c4 * 4 + 2) * D + t];
        float wd = W1[(C + c4 * 4 + 3) * D + t];
        #pragma unroll
        for (int k = 0; k < K; k++) {
            float4 nv = nd4[w][k][c4];
            acc[k] = fmaf(nv.x, wa, acc[k]);
            acc[k] = fmaf(nv.y, wb, acc[k]);
            acc[k] = fmaf(nv.z, wc, acc[k]);
            acc[k] = fmaf(nv.w, wd, acc[k]);
        }
    }
    #pragma unroll
    for (int k = 0; k < K; k++) {
        ((float*)&h14[w][k][0])[t] = gelu_exact(acc[k]);
    }
    __syncthreads();

    float acc2[K];
    float bb = b2[t];
    #pragma unroll
    for (int k = 0; k < K; k++) acc2[k] = bb;
    for (int c4 = 0; c4 < 16; c4++) {
        float wa = W2[(c4 * 4 + 0) * D + t];
        float wb = W2[(c4 * 4 + 1) * D + t];
        float wc = W2[(c4 * 4 + 2) * D + t];
        float wd = W2[(c4 * 4 + 3) * D + t];
        #pragma unroll
        for (int k = 0; k < K; k++) {
            float4 hv = h14[w][k][c4];
            acc2[k] = fmaf(hv.x, wa, acc2[k]);
            acc2[k] = fmaf(hv.y, wb, acc2[k]);
            acc2[k] = fmaf(hv.z, wc, acc2[k]);
            acc2[k] = fmaf(hv.w, wd, acc2[k]);
        }
    }
    float m = -INFINITY;
    #pragma unroll
    for (int k = 0; k < K; k++) m = fmaxf(m, gelu_exact(acc2[k]));

    out[(size_t)qi * D + t] = m;
}

// ---------------------------------------------------------------------------
extern "C" void kernel_launch(void* const* d_in, const int* in_sizes, int n_in,
                              void* d_out, int out_size, void* d_ws, size_t ws_size,
                              hipStream_t stream) {
    const float* F  = (const float*)d_in[0];
    const float* W1 = (const float*)d_in[1];
    const float* b1 = (const float*)d_in[2];
    const float* W2 = (const float*)d_in[3];
    const float* b2 = (const float*)d_in[4];
    float* out = (float*)d_out;

    char* ws = (char*)d_ws;
    float*          sq  = (float*)ws;                             // 128 KB
    int*            knn = (int*)(ws + (128 << 10));               // 2 MB
    unsigned short* HP  = (unsigned short*)(ws + (2176 << 10));   // 4 MB
    unsigned short* MP  = (unsigned short*)(ws + (6272 << 10));   // 4 MB
    unsigned short* LP  = (unsigned short*)(ws + (10368 << 10));  // 4 MB

    prep_kernel<<<dim3(B * N / 256), 256, 0, stream>>>(F, sq, HP, MP, LP);
    knn_mfma_kernel<<<dim3(N / 64, B), 512, 0, stream>>>(HP, MP, LP, sq, knn);
    edgeconv_mlp_kernel<<<dim3(B * N / 4), 256, 0, stream>>>(F, knn, W1, b1, W2, b2, out);
}

// Round 5
// 722.793 us; speedup vs baseline: 1.0833x; 1.0833x over previous
//
#include <hip/hip_runtime.h>
#include <math.h>
#include <stdint.h>

#define B 8
#define N 4096
#define C 64
#define D 64
#define K 16

typedef __attribute__((ext_vector_type(8))) short short8;
typedef __attribute__((ext_vector_type(4))) float f32x4;

// ---------------------------------------------------------------------------
// bf16 helpers
// ---------------------------------------------------------------------------
__device__ __forceinline__ unsigned short f2bf(float x) {
    unsigned u = __float_as_uint(x);
    unsigned r = (u + 0x7FFFu + ((u >> 16) & 1u)) >> 16;   // RNE
    return (unsigned short)r;
}
__device__ __forceinline__ float bf2f(unsigned short h) {
    return __uint_as_float(((unsigned)h) << 16);
}

// ---------------------------------------------------------------------------
// Kernel 0: per-row sqnorm (round-1 arithmetic, passed) + 3-term bf16 split
// ---------------------------------------------------------------------------
__global__ __launch_bounds__(256)
void prep_kernel(const float* __restrict__ F, float* __restrict__ sq,
                 unsigned short* __restrict__ HP, unsigned short* __restrict__ MP,
                 unsigned short* __restrict__ LP) {
    const int row = blockIdx.x * 256 + threadIdx.x;
    const float4* src = (const float4*)(F + (size_t)row * C);
    float4 v[16];
    #pragma unroll
    for (int q = 0; q < 16; q++) v[q] = src[q];

    {
        float r[8];
        #pragma unroll
        for (int j = 0; j < 8; j++) {
            float t = ((const float*)v)[j];
            r[j] = t * t;
        }
        #pragma unroll
        for (int m = 1; m < 8; m++) {
            #pragma unroll
            for (int j = 0; j < 8; j++) {
                float t = ((const float*)v)[8 * m + j];
                r[j] = fmaf(t, t, r[j]);
            }
        }
        sq[row] = ((r[0] + r[1]) + (r[2] + r[3])) + ((r[4] + r[5]) + (r[6] + r[7]));
    }

    uint4* dh = (uint4*)(HP + (size_t)row * C);
    uint4* dm = (uint4*)(MP + (size_t)row * C);
    uint4* dl = (uint4*)(LP + (size_t)row * C);
    #pragma unroll
    for (int c8 = 0; c8 < 8; c8++) {
        unsigned hq[4], mq[4], lq[4];
        #pragma unroll
        for (int e = 0; e < 4; e++) {
            float x0 = ((const float*)v)[c8 * 8 + 2 * e];
            float x1 = ((const float*)v)[c8 * 8 + 2 * e + 1];
            unsigned short h0 = f2bf(x0), h1 = f2bf(x1);
            float r10 = x0 - bf2f(h0), r11 = x1 - bf2f(h1);
            unsigned short m0 = f2bf(r10), m1 = f2bf(r11);
            float r20 = r10 - bf2f(m0), r21 = r11 - bf2f(m1);
            unsigned short l0 = f2bf(r20), l1 = f2bf(r21);
            hq[e] = (unsigned)h0 | ((unsigned)h1 << 16);
            mq[e] = (unsigned)m0 | ((unsigned)m1 << 16);
            lq[e] = (unsigned)l0 | ((unsigned)l1 << 16);
        }
        dh[c8] = make_uint4(hq[0], hq[1], hq[2], hq[3]);
        dm[c8] = make_uint4(mq[0], mq[1], mq[2], mq[3]);
        dl[c8] = make_uint4(lq[0], lq[1], lq[2], lq[3]);
    }
}

// ---------------------------------------------------------------------------
// Kernel 1: MFMA KNN, split-K. Block (x, s, b) = 64 queries x 2048 candidates
// (tiles s*32..s*32+31). Round-3-proven structure: 256 threads / 4 waves,
// u64-key sorted streaming top-16, in-block 4-way tournament -> 16 sorted
// keys per query per half, written to global keys buffer.
// ---------------------------------------------------------------------------
__global__ __launch_bounds__(256)
void knn_mfma_kernel(const unsigned short* __restrict__ HP,
                     const unsigned short* __restrict__ MP,
                     const unsigned short* __restrict__ LP,
                     const float* __restrict__ sqg, uint64_t* __restrict__ keysg) {
    __shared__ __align__(16) char lds[49152];
    char* Qh = lds;             // 8KB each: 64 rows x 128B, XOR-swizzled
    char* Qm = lds + 8192;
    char* Ql = lds + 16384;
    char* Ch = lds + 24576;
    char* Cm = lds + 32768;
    char* Cl = lds + 40960;

    const int s  = blockIdx.y;            // candidate half
    const int b  = blockIdx.z;
    const int i0 = blockIdx.x * 64;
    const int c0 = s * 2048;              // first candidate row of this half
    const unsigned short* Hb = HP + (size_t)b * N * C;
    const unsigned short* Mb = MP + (size_t)b * N * C;
    const unsigned short* Lb = LP + (size_t)b * N * C;
    const float* sqb = sqg + (size_t)b * N;

    const int tid = threadIdx.x;
    const int l   = tid & 63;
    const int w   = tid >> 6;

    const int lr  = tid >> 2;
    const int lq  = tid & 3;
    const int swzW = (lr & 7) << 4;
    const int wb0 = (lr * 128 + lq * 32) ^ swzW;
    const int wb1 = (lr * 128 + lq * 32 + 16) ^ swzW;

    {   // stage Q planes once
        const uint4* sh = (const uint4*)(Hb + (size_t)(i0 + lr) * C + lq * 16);
        const uint4* sm = (const uint4*)(Mb + (size_t)(i0 + lr) * C + lq * 16);
        const uint4* sl = (const uint4*)(Lb + (size_t)(i0 + lr) * C + lq * 16);
        uint4 a0 = sh[0], a1 = sh[1], m0 = sm[0], m1 = sm[1], e0 = sl[0], e1 = sl[1];
        *(uint4*)(Qh + wb0) = a0; *(uint4*)(Qh + wb1) = a1;
        *(uint4*)(Qm + wb0) = m0; *(uint4*)(Qm + wb1) = m1;
        *(uint4*)(Ql + wb0) = e0; *(uint4*)(Ql + wb1) = e1;
    }
    __syncthreads();

    // B fragments (query), register-resident for the whole scan
    const int koff = (l >> 4) * 16;
    const int swzR = (l & 7) << 4;
    const int qrow = w * 16 + (l & 15);
    const int qb0 = (qrow * 128 + koff) ^ swzR;
    const int qb1 = (qrow * 128 + 64 + koff) ^ swzR;
    short8 bh0 = *(const short8*)(Qh + qb0), bh1 = *(const short8*)(Qh + qb1);
    short8 bm0 = *(const short8*)(Qm + qb0), bm1 = *(const short8*)(Qm + qb1);
    short8 bl0 = *(const short8*)(Ql + qb0), bl1 = *(const short8*)(Ql + qb1);

    const float sqq   = sqb[i0 + qrow];
    const int   qglob = i0 + qrow;
    const int   crow0 = (l >> 4) * 4;

    uint64_t bd[16];
    #pragma unroll
    for (int k = 0; k < 16; k++) bd[k] = ~0ull;

    // prefetch first tile of this half
    uint4 ph0, ph1, pm0, pm1, pl0, pl1;
    {
        const size_t rb = (size_t)(c0 + lr) * C + lq * 16;
        const uint4* sh = (const uint4*)(Hb + rb);
        const uint4* sm = (const uint4*)(Mb + rb);
        const uint4* sl = (const uint4*)(Lb + rb);
        ph0 = sh[0]; ph1 = sh[1]; pm0 = sm[0]; pm1 = sm[1]; pl0 = sl[0]; pl1 = sl[1];
    }

    for (int t = 0; t < 32; t++) {
        const int j0 = c0 + t * 64;
        __syncthreads();                        // prior tile's frag reads done
        *(uint4*)(Ch + wb0) = ph0; *(uint4*)(Ch + wb1) = ph1;
        *(uint4*)(Cm + wb0) = pm0; *(uint4*)(Cm + wb1) = pm1;
        *(uint4*)(Cl + wb0) = pl0; *(uint4*)(Cl + wb1) = pl1;
        if (t < 31) {
            const size_t rb = (size_t)(j0 + 64 + lr) * C + lq * 16;
            const uint4* sh = (const uint4*)(Hb + rb);
            const uint4* sm = (const uint4*)(Mb + rb);
            const uint4* sl = (const uint4*)(Lb + rb);
            ph0 = sh[0]; ph1 = sh[1]; pm0 = sm[0]; pm1 = sm[1]; pl0 = sl[0]; pl1 = sl[1];
        }
        __syncthreads();

        float4 sqm0 = *(const float4*)(sqb + j0 +      crow0);
        float4 sqm1 = *(const float4*)(sqb + j0 + 16 + crow0);
        float4 sqm2 = *(const float4*)(sqb + j0 + 32 + crow0);
        float4 sqm3 = *(const float4*)(sqb + j0 + 48 + crow0);

        #pragma unroll
        for (int m = 0; m < 4; m++) {
            const int arow = m * 16 + (l & 15);
            const int ab0 = (arow * 128 + koff) ^ swzR;
            const int ab1 = (arow * 128 + 64 + koff) ^ swzR;
            short8 ah0 = *(const short8*)(Ch + ab0), ah1 = *(const short8*)(Ch + ab1);
            short8 am0 = *(const short8*)(Cm + ab0), am1 = *(const short8*)(Cm + ab1);
            short8 al0 = *(const short8*)(Cl + ab0), al1 = *(const short8*)(Cl + ab1);

            f32x4 accc = {0.f, 0.f, 0.f, 0.f};          // correction terms
            accc = __builtin_amdgcn_mfma_f32_16x16x32_bf16(am0, bm0, accc, 0, 0, 0);
            accc = __builtin_amdgcn_mfma_f32_16x16x32_bf16(am1, bm1, accc, 0, 0, 0);
            accc = __builtin_amdgcn_mfma_f32_16x16x32_bf16(ah0, bl0, accc, 0, 0, 0);
            accc = __builtin_amdgcn_mfma_f32_16x16x32_bf16(ah1, bl1, accc, 0, 0, 0);
            accc = __builtin_amdgcn_mfma_f32_16x16x32_bf16(al0, bh0, accc, 0, 0, 0);
            accc = __builtin_amdgcn_mfma_f32_16x16x32_bf16(al1, bh1, accc, 0, 0, 0);
            accc = __builtin_amdgcn_mfma_f32_16x16x32_bf16(ah0, bm0, accc, 0, 0, 0);
            accc = __builtin_amdgcn_mfma_f32_16x16x32_bf16(ah1, bm1, accc, 0, 0, 0);
            accc = __builtin_amdgcn_mfma_f32_16x16x32_bf16(am0, bh0, accc, 0, 0, 0);
            accc = __builtin_amdgcn_mfma_f32_16x16x32_bf16(am1, bh1, accc, 0, 0, 0);
            f32x4 acch = {0.f, 0.f, 0.f, 0.f};          // hi*hi (dominant)
            acch = __builtin_amdgcn_mfma_f32_16x16x32_bf16(ah0, bh0, acch, 0, 0, 0);
            acch = __builtin_amdgcn_mfma_f32_16x16x32_bf16(ah1, bh1, acch, 0, 0, 0);

            float4 sqm = (m == 0) ? sqm0 : (m == 1) ? sqm1 : (m == 2) ? sqm2 : sqm3;
            #pragma unroll
            for (int r = 0; r < 4; r++) {
                const int cg = j0 + m * 16 + crow0 + r;
                float sqc = (r == 0) ? sqm.x : (r == 1) ? sqm.y : (r == 2) ? sqm.z : sqm.w;
                float gg = acch[r] + accc[r];
                float d2 = fmaf(-2.0f, gg, sqq + sqc);
                if (cg == qglob) d2 = INFINITY;
                d2 = fmaxf(d2, 0.0f);
                uint64_t key = ((uint64_t)__float_as_uint(d2) << 32) | (unsigned)cg;
                if (key < bd[15]) {
                    bool c[16];
                    #pragma unroll
                    for (int k = 0; k < 16; k++) c[k] = key < bd[k];
                    #pragma unroll
                    for (int k = 15; k >= 1; --k)
                        bd[k] = c[k - 1] ? bd[k - 1] : (c[k] ? key : bd[k]);
                    bd[0] = c[0] ? key : bd[0];
                }
            }
        }
    }

    // ---- merge 4 sorted lists per query -> 16 sorted keys for this half ----
    __syncthreads();
    uint64_t* keys = (uint64_t*)lds;           // 32KB reuse
    {
        const int qloc = w * 16 + (l & 15);
        const int sl2  = l >> 4;
        const int base = (qloc * 4 + sl2) * 16;
        #pragma unroll
        for (int k = 0; k < 16; k++) keys[base + k] = bd[k];
    }
    __syncthreads();
    if (tid < 64) {
        const uint64_t* K0 = keys + (tid * 4 + 0) * 16;
        const uint64_t* K1 = keys + (tid * 4 + 1) * 16;
        const uint64_t* K2 = keys + (tid * 4 + 2) * 16;
        const uint64_t* K3 = keys + (tid * 4 + 3) * 16;
        int p0 = 0, p1 = 0, p2 = 0, p3 = 0;
        uint64_t h0 = K0[0], h1 = K1[0], h2 = K2[0], h3 = K3[0];
        uint64_t* dst = keysg + ((size_t)b * N + i0 + tid) * 32 + s * 16;
        #pragma unroll
        for (int k = 0; k < K; k++) {
            uint64_t m01 = h0 < h1 ? h0 : h1;
            uint64_t m23 = h2 < h3 ? h2 : h3;
            uint64_t mv  = m01 < m23 ? m01 : m23;
            dst[k] = mv;
            if      (mv == h0) { ++p0; h0 = (p0 < 16) ? K0[p0] : ~0ull; }
            else if (mv == h1) { ++p1; h1 = (p1 < 16) ? K1[p1] : ~0ull; }
            else if (mv == h2) { ++p2; h2 = (p2 < 16) ? K2[p2] : ~0ull; }
            else               { ++p3; h3 = (p3 < 16) ? K3[p3] : ~0ull; }
        }
    }
}

// ---------------------------------------------------------------------------
// Kernel 1b: final 2-way merge of the two candidate halves, one thread/query
// ---------------------------------------------------------------------------
__global__ __launch_bounds__(256)
void knn_merge_kernel(const uint64_t* __restrict__ keysg, int* __restrict__ knn) {
    const int q = blockIdx.x * 256 + threadIdx.x;     // 0..B*N-1
    const uint64_t* A  = keysg + (size_t)q * 32;
    const uint64_t* Bp = A + 16;
    int pa = 0, pb = 0;
    uint64_t ha = A[0], hb = Bp[0];
    int* dst = knn + (size_t)q * K;
    #pragma unroll
    for (int k = 0; k < K; k++) {
        uint64_t mv = ha < hb ? ha : hb;
        dst[k] = (int)(mv & 0xFFFFFFFFu);
        if (mv == ha) { ++pa; ha = (pa < 16) ? A[pa] : ~0ull; }
        else          { ++pb; hb = (pb < 16) ? Bp[pb] : ~0ull; }
    }
}

// ---------------------------------------------------------------------------
// Kernel 2: gather + 2-layer MLP + max over K (unchanged — passed round 1)
// ---------------------------------------------------------------------------
__device__ __forceinline__ float gelu_exact(float x) {
    return 0.5f * x * (1.0f + erff(x * 0.70710678118654752440f));
}

__global__ __launch_bounds__(256)
void edgeconv_mlp_kernel(const float* __restrict__ F, const int* __restrict__ knn,
                         const float* __restrict__ W1, const float* __restrict__ b1,
                         const float* __restrict__ W2, const float* __restrict__ b2,
                         float* __restrict__ out) {
    __shared__ float4 nd4[4][K][16];
    __shared__ float4 h14[4][K][16];
    __shared__ float  cs[4][64];

    const int tid = threadIdx.x;
    const int w   = tid >> 6;
    const int t   = tid & 63;
    const int qi  = blockIdx.x * 4 + w;
    const int b   = qi >> 12;
    const int i   = qi & (N - 1);
    const float* Fb = F + (size_t)b * N * C;

    float ct = Fb[(size_t)i * C + t];
    cs[w][t] = ct;

    int ids[K];
    const int* kp = knn + (size_t)qi * K;
    #pragma unroll
    for (int k = 0; k < K; k++) ids[k] = kp[k];

    #pragma unroll
    for (int k = 0; k < K; k++) {
        float v = Fb[(size_t)ids[k] * C + t];
        ((float*)&nd4[w][k][0])[t] = v - ct;
    }
    __syncthreads();

    float s0a = b1[t], s0b = 0.f, s0c = 0.f, s0d = 0.f;
    for (int c = 0; c < C; c += 4) {
        s0a = fmaf(cs[w][c + 0], W1[(c + 0) * D + t], s0a);
        s0b = fmaf(cs[w][c + 1], W1[(c + 1) * D + t], s0b);
        s0c = fmaf(cs[w][c + 2], W1[(c + 2) * D + t], s0c);
        s0d = fmaf(cs[w][c + 3], W1[(c + 3) * D + t], s0d);
    }
    float s0 = (s0a + s0b) + (s0c + s0d);

    float acc[K];
    #pragma unroll
    for (int k = 0; k < K; k++) acc[k] = s0;

    for (int c4 = 0; c4 < 16; c4++) {
        float wa = W1[(C + c4 * 4 + 0) * D + t];
        float wb = W1[(C + c4 * 4 + 1) * D + t];
        float wc = W1[(C + c4 * 4 + 2) * D + t];
        float wd = W1[(C + c4 * 4 + 3) * D + t];
        #pragma unroll
        for (int k = 0; k < K; k++) {
            float4 nv = nd4[w][k][c4];
            acc[k] = fmaf(nv.x, wa, acc[k]);
            acc[k] = fmaf(nv.y, wb, acc[k]);
            acc[k] = fmaf(nv.z, wc, acc[k]);
            acc[k] = fmaf(nv.w, wd, acc[k]);
        }
    }
    #pragma unroll
    for (int k = 0; k < K; k++) {
        ((float*)&h14[w][k][0])[t] = gelu_exact(acc[k]);
    }
    __syncthreads();

    float acc2[K];
    float bb = b2[t];
    #pragma unroll
    for (int k = 0; k < K; k++) acc2[k] = bb;
    for (int c4 = 0; c4 < 16; c4++) {
        float wa = W2[(c4 * 4 + 0) * D + t];
        float wb = W2[(c4 * 4 + 1) * D + t];
        float wc = W2[(c4 * 4 + 2) * D + t];
        float wd = W2[(c4 * 4 + 3) * D + t];
        #pragma unroll
        for (int k = 0; k < K; k++) {
            float4 hv = h14[w][k][c4];
            acc2[k] = fmaf(hv.x, wa, acc2[k]);
            acc2[k] = fmaf(hv.y, wb, acc2[k]);
            acc2[k] = fmaf(hv.z, wc, acc2[k]);
            acc2[k] = fmaf(hv.w, wd, acc2[k]);
        }
    }
    float m = -INFINITY;
    #pragma unroll
    for (int k = 0; k < K; k++) m = fmaxf(m, gelu_exact(acc2[k]));

    out[(size_t)qi * D + t] = m;
}

// ---------------------------------------------------------------------------
extern "C" void kernel_launch(void* const* d_in, const int* in_sizes, int n_in,
                              void* d_out, int out_size, void* d_ws, size_t ws_size,
                              hipStream_t stream) {
    const float* F  = (const float*)d_in[0];
    const float* W1 = (const float*)d_in[1];
    const float* b1 = (const float*)d_in[2];
    const float* W2 = (const float*)d_in[3];
    const float* b2 = (const float*)d_in[4];
    float* out = (float*)d_out;

    char* ws = (char*)d_ws;
    float*          sq   = (float*)ws;                             // 128 KB
    uint64_t*       keys = (uint64_t*)(ws + (128 << 10));          // 8 MB
    unsigned short* HP   = (unsigned short*)(ws + (8320 << 10));   // 4 MB
    unsigned short* MP   = (unsigned short*)(ws + (12416 << 10));  // 4 MB
    unsigned short* LP   = (unsigned short*)(ws + (16512 << 10));  // 4 MB
    int*            knn  = (int*)HP;   // HP region dead after knn_mfma pass

    prep_kernel<<<dim3(B * N / 256), 256, 0, stream>>>(F, sq, HP, MP, LP);
    knn_mfma_kernel<<<dim3(N / 64, 2, B), 256, 0, stream>>>(HP, MP, LP, sq, keys);
    knn_merge_kernel<<<dim3(B * N / 256), 256, 0, stream>>>(keys, knn);
    edgeconv_mlp_kernel<<<dim3(B * N / 4), 256, 0, stream>>>(F, knn, W1, b1, W2, b2, out);
}

// Round 6
// 528.354 us; speedup vs baseline: 1.4819x; 1.3680x over previous
//
#include <hip/hip_runtime.h>
#include <math.h>
#include <stdint.h>

#define B 8
#define N 4096
#define C 64
#define D 64
#define K 16

typedef __attribute__((ext_vector_type(8))) short short8;
typedef __attribute__((ext_vector_type(4))) float f32x4;

// ---------------------------------------------------------------------------
// bf16 helpers
// ---------------------------------------------------------------------------
__device__ __forceinline__ unsigned short f2bf(float x) {
    unsigned u = __float_as_uint(x);
    unsigned r = (u + 0x7FFFu + ((u >> 16) & 1u)) >> 16;   // RNE
    return (unsigned short)r;
}
__device__ __forceinline__ float bf2f(unsigned short h) {
    return __uint_as_float(((unsigned)h) << 16);
}

// ---------------------------------------------------------------------------
// Kernel 0: per-row sqnorm (round-1 arithmetic, passed) + 3-term bf16 split
// ---------------------------------------------------------------------------
__global__ __launch_bounds__(256)
void prep_kernel(const float* __restrict__ F, float* __restrict__ sq,
                 unsigned short* __restrict__ HP, unsigned short* __restrict__ MP,
                 unsigned short* __restrict__ LP) {
    const int row = blockIdx.x * 256 + threadIdx.x;
    const float4* src = (const float4*)(F + (size_t)row * C);
    float4 v[16];
    #pragma unroll
    for (int q = 0; q < 16; q++) v[q] = src[q];

    {
        float r[8];
        #pragma unroll
        for (int j = 0; j < 8; j++) {
            float t = ((const float*)v)[j];
            r[j] = t * t;
        }
        #pragma unroll
        for (int m = 1; m < 8; m++) {
            #pragma unroll
            for (int j = 0; j < 8; j++) {
                float t = ((const float*)v)[8 * m + j];
                r[j] = fmaf(t, t, r[j]);
            }
        }
        sq[row] = ((r[0] + r[1]) + (r[2] + r[3])) + ((r[4] + r[5]) + (r[6] + r[7]));
    }

    uint4* dh = (uint4*)(HP + (size_t)row * C);
    uint4* dm = (uint4*)(MP + (size_t)row * C);
    uint4* dl = (uint4*)(LP + (size_t)row * C);
    #pragma unroll
    for (int c8 = 0; c8 < 8; c8++) {
        unsigned hq[4], mq[4], lq[4];
        #pragma unroll
        for (int e = 0; e < 4; e++) {
            float x0 = ((const float*)v)[c8 * 8 + 2 * e];
            float x1 = ((const float*)v)[c8 * 8 + 2 * e + 1];
            unsigned short h0 = f2bf(x0), h1 = f2bf(x1);
            float r10 = x0 - bf2f(h0), r11 = x1 - bf2f(h1);
            unsigned short m0 = f2bf(r10), m1 = f2bf(r11);
            float r20 = r10 - bf2f(m0), r21 = r11 - bf2f(m1);
            unsigned short l0 = f2bf(r20), l1 = f2bf(r21);
            hq[e] = (unsigned)h0 | ((unsigned)h1 << 16);
            mq[e] = (unsigned)m0 | ((unsigned)m1 << 16);
            lq[e] = (unsigned)l0 | ((unsigned)l1 << 16);
        }
        dh[c8] = make_uint4(hq[0], hq[1], hq[2], hq[3]);
        dm[c8] = make_uint4(mq[0], mq[1], mq[2], mq[3]);
        dl[c8] = make_uint4(lq[0], lq[1], lq[2], lq[3]);
    }
}

// ---------------------------------------------------------------------------
// Kernel 1: MFMA KNN (round-3 structure). Block = 64 queries / 4 waves.
// A = candidates, B = queries; lane owns 1 query x 16 cands per tile.
// Selection: branch-free per-tile bitonic merge of 16 new u64 keys into the
// sorted-ascending top-16 (keys = d2bits<<32 | idx -> exact tie-break).
// ---------------------------------------------------------------------------
__global__ __launch_bounds__(256)
void knn_mfma_kernel(const unsigned short* __restrict__ HP,
                     const unsigned short* __restrict__ MP,
                     const unsigned short* __restrict__ LP,
                     const float* __restrict__ sqg, int* __restrict__ knn) {
    __shared__ __align__(16) char lds[49152];
    char* Qh = lds;             // 8KB each: 64 rows x 128B, XOR-swizzled
    char* Qm = lds + 8192;
    char* Ql = lds + 16384;
    char* Ch = lds + 24576;
    char* Cm = lds + 32768;
    char* Cl = lds + 40960;

    const int b  = blockIdx.y;
    const int i0 = blockIdx.x * 64;
    const unsigned short* Hb = HP + (size_t)b * N * C;
    const unsigned short* Mb = MP + (size_t)b * N * C;
    const unsigned short* Lb = LP + (size_t)b * N * C;
    const float* sqb = sqg + (size_t)b * N;

    const int tid = threadIdx.x;
    const int l   = tid & 63;
    const int w   = tid >> 6;

    const int lr  = tid >> 2;
    const int lq  = tid & 3;
    const int swzW = (lr & 7) << 4;
    const int wb0 = (lr * 128 + lq * 32) ^ swzW;
    const int wb1 = (lr * 128 + lq * 32 + 16) ^ swzW;

    {   // stage Q planes once
        const uint4* sh = (const uint4*)(Hb + (size_t)(i0 + lr) * C + lq * 16);
        const uint4* sm = (const uint4*)(Mb + (size_t)(i0 + lr) * C + lq * 16);
        const uint4* sl = (const uint4*)(Lb + (size_t)(i0 + lr) * C + lq * 16);
        uint4 a0 = sh[0], a1 = sh[1], m0 = sm[0], m1 = sm[1], e0 = sl[0], e1 = sl[1];
        *(uint4*)(Qh + wb0) = a0; *(uint4*)(Qh + wb1) = a1;
        *(uint4*)(Qm + wb0) = m0; *(uint4*)(Qm + wb1) = m1;
        *(uint4*)(Ql + wb0) = e0; *(uint4*)(Ql + wb1) = e1;
    }
    __syncthreads();

    // B fragments (query), register-resident for the whole scan
    const int koff = (l >> 4) * 16;
    const int swzR = (l & 7) << 4;
    const int qrow = w * 16 + (l & 15);
    const int qb0 = (qrow * 128 + koff) ^ swzR;
    const int qb1 = (qrow * 128 + 64 + koff) ^ swzR;
    short8 bh0 = *(const short8*)(Qh + qb0), bh1 = *(const short8*)(Qh + qb1);
    short8 bm0 = *(const short8*)(Qm + qb0), bm1 = *(const short8*)(Qm + qb1);
    short8 bl0 = *(const short8*)(Ql + qb0), bl1 = *(const short8*)(Ql + qb1);

    const float sqq   = sqb[i0 + qrow];
    const int   qglob = i0 + qrow;
    const int   crow0 = (l >> 4) * 4;

    uint64_t bd[16];
    #pragma unroll
    for (int k = 0; k < 16; k++) bd[k] = ~0ull;

    // prefetch tile 0
    uint4 ph0, ph1, pm0, pm1, pl0, pl1;
    {
        const size_t rb = (size_t)lr * C + lq * 16;
        const uint4* sh = (const uint4*)(Hb + rb);
        const uint4* sm = (const uint4*)(Mb + rb);
        const uint4* sl = (const uint4*)(Lb + rb);
        ph0 = sh[0]; ph1 = sh[1]; pm0 = sm[0]; pm1 = sm[1]; pl0 = sl[0]; pl1 = sl[1];
    }

    for (int t = 0; t < 64; t++) {
        const int j0 = t * 64;
        __syncthreads();                        // prior tile's frag reads done
        *(uint4*)(Ch + wb0) = ph0; *(uint4*)(Ch + wb1) = ph1;
        *(uint4*)(Cm + wb0) = pm0; *(uint4*)(Cm + wb1) = pm1;
        *(uint4*)(Cl + wb0) = pl0; *(uint4*)(Cl + wb1) = pl1;
        if (t < 63) {
            const size_t rb = (size_t)(j0 + 64 + lr) * C + lq * 16;
            const uint4* sh = (const uint4*)(Hb + rb);
            const uint4* sm = (const uint4*)(Mb + rb);
            const uint4* sl = (const uint4*)(Lb + rb);
            ph0 = sh[0]; ph1 = sh[1]; pm0 = sm[0]; pm1 = sm[1]; pl0 = sl[0]; pl1 = sl[1];
        }
        __syncthreads();

        float4 sqm0 = *(const float4*)(sqb + j0 +      crow0);
        float4 sqm1 = *(const float4*)(sqb + j0 + 16 + crow0);
        float4 sqm2 = *(const float4*)(sqb + j0 + 32 + crow0);
        float4 sqm3 = *(const float4*)(sqb + j0 + 48 + crow0);

        uint64_t nk[16];

        #pragma unroll
        for (int m = 0; m < 4; m++) {
            const int arow = m * 16 + (l & 15);
            const int ab0 = (arow * 128 + koff) ^ swzR;
            const int ab1 = (arow * 128 + 64 + koff) ^ swzR;
            short8 ah0 = *(const short8*)(Ch + ab0), ah1 = *(const short8*)(Ch + ab1);
            short8 am0 = *(const short8*)(Cm + ab0), am1 = *(const short8*)(Cm + ab1);
            short8 al0 = *(const short8*)(Cl + ab0), al1 = *(const short8*)(Cl + ab1);

            // three independent MFMA chains (depth 5/5/2) to cut latency stalls
            f32x4 acc1 = {0.f, 0.f, 0.f, 0.f};
            acc1 = __builtin_amdgcn_mfma_f32_16x16x32_bf16(am0, bm0, acc1, 0, 0, 0);
            acc1 = __builtin_amdgcn_mfma_f32_16x16x32_bf16(am1, bm1, acc1, 0, 0, 0);
            acc1 = __builtin_amdgcn_mfma_f32_16x16x32_bf16(ah0, bl0, acc1, 0, 0, 0);
            acc1 = __builtin_amdgcn_mfma_f32_16x16x32_bf16(ah1, bl1, acc1, 0, 0, 0);
            acc1 = __builtin_amdgcn_mfma_f32_16x16x32_bf16(al0, bh0, acc1, 0, 0, 0);
            f32x4 acc2 = {0.f, 0.f, 0.f, 0.f};
            acc2 = __builtin_amdgcn_mfma_f32_16x16x32_bf16(al1, bh1, acc2, 0, 0, 0);
            acc2 = __builtin_amdgcn_mfma_f32_16x16x32_bf16(ah0, bm0, acc2, 0, 0, 0);
            acc2 = __builtin_amdgcn_mfma_f32_16x16x32_bf16(ah1, bm1, acc2, 0, 0, 0);
            acc2 = __builtin_amdgcn_mfma_f32_16x16x32_bf16(am0, bh0, acc2, 0, 0, 0);
            acc2 = __builtin_amdgcn_mfma_f32_16x16x32_bf16(am1, bh1, acc2, 0, 0, 0);
            f32x4 acch = {0.f, 0.f, 0.f, 0.f};
            acch = __builtin_amdgcn_mfma_f32_16x16x32_bf16(ah0, bh0, acch, 0, 0, 0);
            acch = __builtin_amdgcn_mfma_f32_16x16x32_bf16(ah1, bh1, acch, 0, 0, 0);

            float4 sqm = (m == 0) ? sqm0 : (m == 1) ? sqm1 : (m == 2) ? sqm2 : sqm3;
            #pragma unroll
            for (int r = 0; r < 4; r++) {
                float sqc = (r == 0) ? sqm.x : (r == 1) ? sqm.y : (r == 2) ? sqm.z : sqm.w;
                float gg = acch[r] + (acc1[r] + acc2[r]);
                float d2 = fmaf(-2.0f, gg, sqq + sqc);
                d2 = fmaxf(d2, 0.0f);                    // asuint monotonic
                nk[m * 4 + r] = ((uint64_t)__float_as_uint(d2) << 32)
                              | (unsigned)(j0 + m * 16 + crow0 + r);
            }
        }

        // diagonal tile only: kill self-match (wave-uniform branch)
        if (j0 == i0) {
            #pragma unroll
            for (int m = 0; m < 4; m++)
                #pragma unroll
                for (int r = 0; r < 4; r++)
                    if ((j0 + m * 16 + crow0 + r) == qglob) nk[m * 4 + r] = ~0ull;
        }

        // ---- bitonic sort nk DESCENDING (fully unrolled, branch-free) ----
        #pragma unroll
        for (int kk = 2; kk <= 16; kk <<= 1) {
            #pragma unroll
            for (int j = kk >> 1; j > 0; j >>= 1) {
                #pragma unroll
                for (int i = 0; i < 16; i++) {
                    int ixj = i ^ j;
                    if (ixj > i) {
                        bool asc = ((i & kk) != 0);      // overall descending
                        uint64_t a = nk[i], c = nk[ixj];
                        bool sw = asc ? (c < a) : (a < c);
                        nk[i]   = sw ? c : a;
                        nk[ixj] = sw ? a : c;
                    }
                }
            }
        }
        // ---- lowest-16 of (bd asc ++ nk desc): elementwise min ----
        #pragma unroll
        for (int i = 0; i < 16; i++) {
            uint64_t a = bd[i], c = nk[i];
            bd[i] = (c < a) ? c : a;
        }
        // ---- bd is bitonic: clean to ascending (strides 8,4,2,1) ----
        #pragma unroll
        for (int j = 8; j > 0; j >>= 1) {
            #pragma unroll
            for (int i = 0; i < 16; i++) {
                int ixj = i ^ j;
                if (ixj > i) {
                    uint64_t a = bd[i], c = bd[ixj];
                    bool sw = c < a;
                    bd[i]   = sw ? c : a;
                    bd[ixj] = sw ? a : c;
                }
            }
        }
    }

    // ---- merge 4 sorted lists per query -> top-16 indices ----
    __syncthreads();
    uint64_t* keys = (uint64_t*)lds;           // 32KB reuse
    {
        const int qloc = w * 16 + (l & 15);
        const int sl2  = l >> 4;
        const int base = (qloc * 4 + sl2) * 16;
        #pragma unroll
        for (int k = 0; k < 16; k++) keys[base + k] = bd[k];
    }
    __syncthreads();
    if (tid < 64) {
        const uint64_t* K0 = keys + (tid * 4 + 0) * 16;
        const uint64_t* K1 = keys + (tid * 4 + 1) * 16;
        const uint64_t* K2 = keys + (tid * 4 + 2) * 16;
        const uint64_t* K3 = keys + (tid * 4 + 3) * 16;
        int p0 = 0, p1 = 0, p2 = 0, p3 = 0;
        uint64_t h0 = K0[0], h1 = K1[0], h2 = K2[0], h3 = K3[0];
        int* dst = knn + ((size_t)b * N + i0 + tid) * K;
        #pragma unroll
        for (int k = 0; k < K; k++) {
            uint64_t m01 = h0 < h1 ? h0 : h1;
            uint64_t m23 = h2 < h3 ? h2 : h3;
            uint64_t mv  = m01 < m23 ? m01 : m23;
            dst[k] = (int)(mv & 0xFFFFFFFFu);
            if      (mv == h0) { ++p0; h0 = (p0 < 16) ? K0[p0] : ~0ull; }
            else if (mv == h1) { ++p1; h1 = (p1 < 16) ? K1[p1] : ~0ull; }
            else if (mv == h2) { ++p2; h2 = (p2 < 16) ? K2[p2] : ~0ull; }
            else               { ++p3; h3 = (p3 < 16) ? K3[p3] : ~0ull; }
        }
    }
}

// ---------------------------------------------------------------------------
// Kernel 2: gather + 2-layer MLP + max over K (unchanged — passed round 1)
// ---------------------------------------------------------------------------
__device__ __forceinline__ float gelu_exact(float x) {
    return 0.5f * x * (1.0f + erff(x * 0.70710678118654752440f));
}

__global__ __launch_bounds__(256)
void edgeconv_mlp_kernel(const float* __restrict__ F, const int* __restrict__ knn,
                         const float* __restrict__ W1, const float* __restrict__ b1,
                         const float* __restrict__ W2, const float* __restrict__ b2,
                         float* __restrict__ out) {
    __shared__ float4 nd4[4][K][16];
    __shared__ float4 h14[4][K][16];
    __shared__ float  cs[4][64];

    const int tid = threadIdx.x;
    const int w   = tid >> 6;
    const int t   = tid & 63;
    const int qi  = blockIdx.x * 4 + w;
    const int b   = qi >> 12;
    const int i   = qi & (N - 1);
    const float* Fb = F + (size_t)b * N * C;

    float ct = Fb[(size_t)i * C + t];
    cs[w][t] = ct;

    int ids[K];
    const int* kp = knn + (size_t)qi * K;
    #pragma unroll
    for (int k = 0; k < K; k++) ids[k] = kp[k];

    #pragma unroll
    for (int k = 0; k < K; k++) {
        float v = Fb[(size_t)ids[k] * C + t];
        ((float*)&nd4[w][k][0])[t] = v - ct;
    }
    __syncthreads();

    float s0a = b1[t], s0b = 0.f, s0c = 0.f, s0d = 0.f;
    for (int c = 0; c < C; c += 4) {
        s0a = fmaf(cs[w][c + 0], W1[(c + 0) * D + t], s0a);
        s0b = fmaf(cs[w][c + 1], W1[(c + 1) * D + t], s0b);
        s0c = fmaf(cs[w][c + 2], W1[(c + 2) * D + t], s0c);
        s0d = fmaf(cs[w][c + 3], W1[(c + 3) * D + t], s0d);
    }
    float s0 = (s0a + s0b) + (s0c + s0d);

    float acc[K];
    #pragma unroll
    for (int k = 0; k < K; k++) acc[k] = s0;

    for (int c4 = 0; c4 < 16; c4++) {
        float wa = W1[(C + c4 * 4 + 0) * D + t];
        float wb = W1[(C + c4 * 4 + 1) * D + t];
        float wc = W1[(C + c4 * 4 + 2) * D + t];
        float wd = W1[(C + c4 * 4 + 3) * D + t];
        #pragma unroll
        for (int k = 0; k < K; k++) {
            float4 nv = nd4[w][k][c4];
            acc[k] = fmaf(nv.x, wa, acc[k]);
            acc[k] = fmaf(nv.y, wb, acc[k]);
            acc[k] = fmaf(nv.z, wc, acc[k]);
            acc[k] = fmaf(nv.w, wd, acc[k]);
        }
    }
    #pragma unroll
    for (int k = 0; k < K; k++) {
        ((float*)&h14[w][k][0])[t] = gelu_exact(acc[k]);
    }
    __syncthreads();

    float acc2[K];
    float bb = b2[t];
    #pragma unroll
    for (int k = 0; k < K; k++) acc2[k] = bb;
    for (int c4 = 0; c4 < 16; c4++) {
        float wa = W2[(c4 * 4 + 0) * D + t];
        float wb = W2[(c4 * 4 + 1) * D + t];
        float wc = W2[(c4 * 4 + 2) * D + t];
        float wd = W2[(c4 * 4 + 3) * D + t];
        #pragma unroll
        for (int k = 0; k < K; k++) {
            float4 hv = h14[w][k][c4];
            acc2[k] = fmaf(hv.x, wa, acc2[k]);
            acc2[k] = fmaf(hv.y, wb, acc2[k]);
            acc2[k] = fmaf(hv.z, wc, acc2[k]);
            acc2[k] = fmaf(hv.w, wd, acc2[k]);
        }
    }
    float m = -INFINITY;
    #pragma unroll
    for (int k = 0; k < K; k++) m = fmaxf(m, gelu_exact(acc2[k]));

    out[(size_t)qi * D + t] = m;
}

// ---------------------------------------------------------------------------
extern "C" void kernel_launch(void* const* d_in, const int* in_sizes, int n_in,
                              void* d_out, int out_size, void* d_ws, size_t ws_size,
                              hipStream_t stream) {
    const float* F  = (const float*)d_in[0];
    const float* W1 = (const float*)d_in[1];
    const float* b1 = (const float*)d_in[2];
    const float* W2 = (const float*)d_in[3];
    const float* b2 = (const float*)d_in[4];
    float* out = (float*)d_out;

    char* ws = (char*)d_ws;
    float*          sq  = (float*)ws;                             // 128 KB
    int*            knn = (int*)(ws + (128 << 10));               // 2 MB
    unsigned short* HP  = (unsigned short*)(ws + (2176 << 10));   // 4 MB
    unsigned short* MP  = (unsigned short*)(ws + (6272 << 10));   // 4 MB
    unsigned short* LP  = (unsigned short*)(ws + (10368 << 10));  // 4 MB

    prep_kernel<<<dim3(B * N / 256), 256, 0, stream>>>(F, sq, HP, MP, LP);
    knn_mfma_kernel<<<dim3(N / 64, B), 256, 0, stream>>>(HP, MP, LP, sq, knn);
    edgeconv_mlp_kernel<<<dim3(B * N / 4), 256, 0, stream>>>(F, knn, W1, b1, W2, b2, out);
}

// Round 7
// 385.929 us; speedup vs baseline: 2.0288x; 1.3690x over previous
//
#include <hip/hip_runtime.h>
#include <math.h>
#include <stdint.h>

#define B 8
#define N 4096
#define C 64
#define D 64
#define K 16

typedef __attribute__((ext_vector_type(8))) short short8;
typedef __attribute__((ext_vector_type(4))) float f32x4;

// ---------------------------------------------------------------------------
// bf16 helpers
// ---------------------------------------------------------------------------
__device__ __forceinline__ unsigned short f2bf(float x) {
    unsigned u = __float_as_uint(x);
    unsigned r = (u + 0x7FFFu + ((u >> 16) & 1u)) >> 16;   // RNE
    return (unsigned short)r;
}
__device__ __forceinline__ float bf2f(unsigned short h) {
    return __uint_as_float(((unsigned)h) << 16);
}

// key = (d2bits<<32)|idx reinterpreted as double. d2 finite >=0 -> positive
// finite double -> IEEE ordering == integer ordering (exact tie-break kept).
__device__ __forceinline__ double pack_key(float d2, unsigned idx) {
    uint2 u; u.x = idx; u.y = __float_as_uint(d2);
    return __builtin_bit_cast(double, u);
}

// ---------------------------------------------------------------------------
// Kernel 0: per-row sqnorm (round-1 arithmetic, passed) + 3-term bf16 split
// ---------------------------------------------------------------------------
__global__ __launch_bounds__(256)
void prep_kernel(const float* __restrict__ F, float* __restrict__ sq,
                 unsigned short* __restrict__ HP, unsigned short* __restrict__ MP,
                 unsigned short* __restrict__ LP) {
    const int row = blockIdx.x * 256 + threadIdx.x;
    const float4* src = (const float4*)(F + (size_t)row * C);
    float4 v[16];
    #pragma unroll
    for (int q = 0; q < 16; q++) v[q] = src[q];

    {
        float r[8];
        #pragma unroll
        for (int j = 0; j < 8; j++) {
            float t = ((const float*)v)[j];
            r[j] = t * t;
        }
        #pragma unroll
        for (int m = 1; m < 8; m++) {
            #pragma unroll
            for (int j = 0; j < 8; j++) {
                float t = ((const float*)v)[8 * m + j];
                r[j] = fmaf(t, t, r[j]);
            }
        }
        sq[row] = ((r[0] + r[1]) + (r[2] + r[3])) + ((r[4] + r[5]) + (r[6] + r[7]));
    }

    uint4* dh = (uint4*)(HP + (size_t)row * C);
    uint4* dm = (uint4*)(MP + (size_t)row * C);
    uint4* dl = (uint4*)(LP + (size_t)row * C);
    #pragma unroll
    for (int c8 = 0; c8 < 8; c8++) {
        unsigned hq[4], mq[4], lq[4];
        #pragma unroll
        for (int e = 0; e < 4; e++) {
            float x0 = ((const float*)v)[c8 * 8 + 2 * e];
            float x1 = ((const float*)v)[c8 * 8 + 2 * e + 1];
            unsigned short h0 = f2bf(x0), h1 = f2bf(x1);
            float r10 = x0 - bf2f(h0), r11 = x1 - bf2f(h1);
            unsigned short m0 = f2bf(r10), m1 = f2bf(r11);
            float r20 = r10 - bf2f(m0), r21 = r11 - bf2f(m1);
            unsigned short l0 = f2bf(r20), l1 = f2bf(r21);
            hq[e] = (unsigned)h0 | ((unsigned)h1 << 16);
            mq[e] = (unsigned)m0 | ((unsigned)m1 << 16);
            lq[e] = (unsigned)l0 | ((unsigned)l1 << 16);
        }
        dh[c8] = make_uint4(hq[0], hq[1], hq[2], hq[3]);
        dm[c8] = make_uint4(mq[0], mq[1], mq[2], mq[3]);
        dl[c8] = make_uint4(lq[0], lq[1], lq[2], lq[3]);
    }
}

// ---------------------------------------------------------------------------
// Kernel 1: MFMA KNN. Round-6 structure + (a) f64 fmin/fmax selection network
// (2-instr CAS, identical ordering semantics), (b) LDS double-buffer: Q region
// becomes second C buffer; 1 barrier/tile, ds_writes overlap compute.
// ---------------------------------------------------------------------------
__global__ __launch_bounds__(256)
void knn_mfma_kernel(const unsigned short* __restrict__ HP,
                     const unsigned short* __restrict__ MP,
                     const unsigned short* __restrict__ LP,
                     const float* __restrict__ sqg, int* __restrict__ knn) {
    __shared__ __align__(16) char lds[49152];   // buf0 = [0,24K), buf1 = [24K,48K)

    const int b  = blockIdx.y;
    const int i0 = blockIdx.x * 64;
    const unsigned short* Hb = HP + (size_t)b * N * C;
    const unsigned short* Mb = MP + (size_t)b * N * C;
    const unsigned short* Lb = LP + (size_t)b * N * C;
    const float* sqb = sqg + (size_t)b * N;

    const int tid = threadIdx.x;
    const int l   = tid & 63;
    const int w   = tid >> 6;

    const int lr  = tid >> 2;
    const int lq  = tid & 3;
    const int swzW = (lr & 7) << 4;
    const int wb0 = (lr * 128 + lq * 32) ^ swzW;
    const int wb1 = (lr * 128 + lq * 32 + 16) ^ swzW;

    const double KMAX = __builtin_bit_cast(double, 0x7FEFFFFFFFFFFFFFull);

    // prefetch tile 0 regs first (hides under Q staging)
    uint4 ph0, ph1, pm0, pm1, pl0, pl1;
    {
        const size_t rb = (size_t)lr * C + lq * 16;
        const uint4* sh = (const uint4*)(Hb + rb);
        const uint4* sm = (const uint4*)(Mb + rb);
        const uint4* sl = (const uint4*)(Lb + rb);
        ph0 = sh[0]; ph1 = sh[1]; pm0 = sm[0]; pm1 = sm[1]; pl0 = sl[0]; pl1 = sl[1];
    }

    {   // stage Q planes into buf0
        const uint4* sh = (const uint4*)(Hb + (size_t)(i0 + lr) * C + lq * 16);
        const uint4* sm = (const uint4*)(Mb + (size_t)(i0 + lr) * C + lq * 16);
        const uint4* sl = (const uint4*)(Lb + (size_t)(i0 + lr) * C + lq * 16);
        uint4 a0 = sh[0], a1 = sh[1], m0 = sm[0], m1 = sm[1], e0 = sl[0], e1 = sl[1];
        *(uint4*)(lds +         wb0) = a0; *(uint4*)(lds +         wb1) = a1;
        *(uint4*)(lds +  8192 + wb0) = m0; *(uint4*)(lds +  8192 + wb1) = m1;
        *(uint4*)(lds + 16384 + wb0) = e0; *(uint4*)(lds + 16384 + wb1) = e1;
    }
    __syncthreads();

    // B fragments (query), register-resident for the whole scan
    const int koff = (l >> 4) * 16;
    const int swzR = (l & 7) << 4;
    const int qrow = w * 16 + (l & 15);
    const int qb0 = (qrow * 128 + koff) ^ swzR;
    const int qb1 = (qrow * 128 + 64 + koff) ^ swzR;
    short8 bh0 = *(const short8*)(lds + qb0),         bh1 = *(const short8*)(lds + qb1);
    short8 bm0 = *(const short8*)(lds +  8192 + qb0), bm1 = *(const short8*)(lds +  8192 + qb1);
    short8 bl0 = *(const short8*)(lds + 16384 + qb0), bl1 = *(const short8*)(lds + 16384 + qb1);

    const float sqq   = sqb[i0 + qrow];
    const int   qglob = i0 + qrow;
    const int   crow0 = (l >> 4) * 4;

    __syncthreads();          // all waves finished reading Q from buf0

    // stage tile 0 into buf0 (overwrites Q region)
    *(uint4*)(lds +         wb0) = ph0; *(uint4*)(lds +         wb1) = ph1;
    *(uint4*)(lds +  8192 + wb0) = pm0; *(uint4*)(lds +  8192 + wb1) = pm1;
    *(uint4*)(lds + 16384 + wb0) = pl0; *(uint4*)(lds + 16384 + wb1) = pl1;

    // prefetch tile 1
    {
        const size_t rb = (size_t)(64 + lr) * C + lq * 16;
        const uint4* sh = (const uint4*)(Hb + rb);
        const uint4* sm = (const uint4*)(Mb + rb);
        const uint4* sl = (const uint4*)(Lb + rb);
        ph0 = sh[0]; ph1 = sh[1]; pm0 = sm[0]; pm1 = sm[1]; pl0 = sl[0]; pl1 = sl[1];
    }
    __syncthreads();          // tile 0 visible

    double bd[16];
    #pragma unroll
    for (int k = 0; k < 16; k++) bd[k] = KMAX;

    for (int t = 0; t < 64; t++) {
        const int j0 = t * 64;
        char* bufA = lds + ((t & 1) ? 24576 : 0);      // compute tile t
        char* bufB = lds + ((t & 1) ? 0 : 24576);      // stage tile t+1

        // 1) stage tile t+1 (drains under the compute below)
        if (t < 63) {
            *(uint4*)(bufB +         wb0) = ph0; *(uint4*)(bufB +         wb1) = ph1;
            *(uint4*)(bufB +  8192 + wb0) = pm0; *(uint4*)(bufB +  8192 + wb1) = pm1;
            *(uint4*)(bufB + 16384 + wb0) = pl0; *(uint4*)(bufB + 16384 + wb1) = pl1;
        }
        // 2) prefetch tile t+2 (in flight across the barrier)
        if (t < 62) {
            const size_t rb = (size_t)(j0 + 128 + lr) * C + lq * 16;
            const uint4* sh = (const uint4*)(Hb + rb);
            const uint4* sm = (const uint4*)(Mb + rb);
            const uint4* sl = (const uint4*)(Lb + rb);
            ph0 = sh[0]; ph1 = sh[1]; pm0 = sm[0]; pm1 = sm[1]; pl0 = sl[0]; pl1 = sl[1];
        }

        float4 sqm0 = *(const float4*)(sqb + j0 +      crow0);
        float4 sqm1 = *(const float4*)(sqb + j0 + 16 + crow0);
        float4 sqm2 = *(const float4*)(sqb + j0 + 32 + crow0);
        float4 sqm3 = *(const float4*)(sqb + j0 + 48 + crow0);

        double nk[16];

        #pragma unroll
        for (int m = 0; m < 4; m++) {
            const int arow = m * 16 + (l & 15);
            const int ab0 = (arow * 128 + koff) ^ swzR;
            const int ab1 = (arow * 128 + 64 + koff) ^ swzR;
            short8 ah0 = *(const short8*)(bufA + ab0);
            short8 ah1 = *(const short8*)(bufA + ab1);
            short8 am0 = *(const short8*)(bufA + 8192 + ab0);
            short8 am1 = *(const short8*)(bufA + 8192 + ab1);
            short8 al0 = *(const short8*)(bufA + 16384 + ab0);
            short8 al1 = *(const short8*)(bufA + 16384 + ab1);

            // three independent MFMA chains (depth 5/5/2)
            f32x4 acc1 = {0.f, 0.f, 0.f, 0.f};
            acc1 = __builtin_amdgcn_mfma_f32_16x16x32_bf16(am0, bm0, acc1, 0, 0, 0);
            acc1 = __builtin_amdgcn_mfma_f32_16x16x32_bf16(am1, bm1, acc1, 0, 0, 0);
            acc1 = __builtin_amdgcn_mfma_f32_16x16x32_bf16(ah0, bl0, acc1, 0, 0, 0);
            acc1 = __builtin_amdgcn_mfma_f32_16x16x32_bf16(ah1, bl1, acc1, 0, 0, 0);
            acc1 = __builtin_amdgcn_mfma_f32_16x16x32_bf16(al0, bh0, acc1, 0, 0, 0);
            f32x4 acc2 = {0.f, 0.f, 0.f, 0.f};
            acc2 = __builtin_amdgcn_mfma_f32_16x16x32_bf16(al1, bh1, acc2, 0, 0, 0);
            acc2 = __builtin_amdgcn_mfma_f32_16x16x32_bf16(ah0, bm0, acc2, 0, 0, 0);
            acc2 = __builtin_amdgcn_mfma_f32_16x16x32_bf16(ah1, bm1, acc2, 0, 0, 0);
            acc2 = __builtin_amdgcn_mfma_f32_16x16x32_bf16(am0, bh0, acc2, 0, 0, 0);
            acc2 = __builtin_amdgcn_mfma_f32_16x16x32_bf16(am1, bh1, acc2, 0, 0, 0);
            f32x4 acch = {0.f, 0.f, 0.f, 0.f};
            acch = __builtin_amdgcn_mfma_f32_16x16x32_bf16(ah0, bh0, acch, 0, 0, 0);
            acch = __builtin_amdgcn_mfma_f32_16x16x32_bf16(ah1, bh1, acch, 0, 0, 0);

            float4 sqm = (m == 0) ? sqm0 : (m == 1) ? sqm1 : (m == 2) ? sqm2 : sqm3;
            #pragma unroll
            for (int r = 0; r < 4; r++) {
                float sqc = (r == 0) ? sqm.x : (r == 1) ? sqm.y : (r == 2) ? sqm.z : sqm.w;
                float gg = acch[r] + (acc1[r] + acc2[r]);
                float d2 = fmaf(-2.0f, gg, sqq + sqc);
                d2 = fmaxf(d2, 0.0f);                    // monotonic bits, positive
                nk[m * 4 + r] = pack_key(d2, (unsigned)(j0 + m * 16 + crow0 + r));
            }
        }

        // diagonal tile only: kill self-match (wave-uniform branch)
        if (j0 == i0) {
            #pragma unroll
            for (int m = 0; m < 4; m++)
                #pragma unroll
                for (int r = 0; r < 4; r++)
                    if ((j0 + m * 16 + crow0 + r) == qglob) nk[m * 4 + r] = KMAX;
        }

        // ---- bitonic sort nk DESCENDING via fmin/fmax (2-instr CAS) ----
        #pragma unroll
        for (int kk = 2; kk <= 16; kk <<= 1) {
            #pragma unroll
            for (int j = kk >> 1; j > 0; j >>= 1) {
                #pragma unroll
                for (int i = 0; i < 16; i++) {
                    int ixj = i ^ j;
                    if (ixj > i) {
                        bool asc = ((i & kk) != 0);      // compile-time
                        double a = nk[i], c = nk[ixj];
                        nk[i]   = asc ? fmin(a, c) : fmax(a, c);
                        nk[ixj] = asc ? fmax(a, c) : fmin(a, c);
                    }
                }
            }
        }
        // ---- lowest-16 of (bd asc ++ nk desc): elementwise min ----
        #pragma unroll
        for (int i = 0; i < 16; i++) bd[i] = fmin(bd[i], nk[i]);
        // ---- bd bitonic -> ascending cleanup (strides 8,4,2,1) ----
        #pragma unroll
        for (int j = 8; j > 0; j >>= 1) {
            #pragma unroll
            for (int i = 0; i < 16; i++) {
                int ixj = i ^ j;
                if (ixj > i) {
                    double a = bd[i], c = bd[ixj];
                    bd[i]   = fmin(a, c);
                    bd[ixj] = fmax(a, c);
                }
            }
        }

        __syncthreads();       // tile t+1 staged & prior reads done
    }

    // ---- merge 4 sorted lists per query -> top-16 indices ----
    uint64_t* keys = (uint64_t*)lds;           // 32KB reuse
    {
        const int qloc = w * 16 + (l & 15);
        const int sl2  = l >> 4;
        const int base = (qloc * 4 + sl2) * 16;
        #pragma unroll
        for (int k = 0; k < 16; k++)
            keys[base + k] = __builtin_bit_cast(uint64_t, bd[k]);
    }
    __syncthreads();
    if (tid < 64) {
        const uint64_t* K0 = keys + (tid * 4 + 0) * 16;
        const uint64_t* K1 = keys + (tid * 4 + 1) * 16;
        const uint64_t* K2 = keys + (tid * 4 + 2) * 16;
        const uint64_t* K3 = keys + (tid * 4 + 3) * 16;
        int p0 = 0, p1 = 0, p2 = 0, p3 = 0;
        uint64_t h0 = K0[0], h1 = K1[0], h2 = K2[0], h3 = K3[0];
        int* dst = knn + ((size_t)b * N + i0 + tid) * K;
        #pragma unroll
        for (int k = 0; k < K; k++) {
            uint64_t m01 = h0 < h1 ? h0 : h1;
            uint64_t m23 = h2 < h3 ? h2 : h3;
            uint64_t mv  = m01 < m23 ? m01 : m23;
            dst[k] = (int)(mv & 0xFFFFFFFFu);
            if      (mv == h0) { ++p0; h0 = (p0 < 16) ? K0[p0] : ~0ull; }
            else if (mv == h1) { ++p1; h1 = (p1 < 16) ? K1[p1] : ~0ull; }
            else if (mv == h2) { ++p2; h2 = (p2 < 16) ? K2[p2] : ~0ull; }
            else               { ++p3; h3 = (p3 < 16) ? K3[p3] : ~0ull; }
        }
    }
}

// ---------------------------------------------------------------------------
// Kernel 2: gather + 2-layer MLP + max over K (unchanged — passed round 1)
// ---------------------------------------------------------------------------
__device__ __forceinline__ float gelu_exact(float x) {
    return 0.5f * x * (1.0f + erff(x * 0.70710678118654752440f));
}

__global__ __launch_bounds__(256)
void edgeconv_mlp_kernel(const float* __restrict__ F, const int* __restrict__ knn,
                         const float* __restrict__ W1, const float* __restrict__ b1,
                         const float* __restrict__ W2, const float* __restrict__ b2,
                         float* __restrict__ out) {
    __shared__ float4 nd4[4][K][16];
    __shared__ float4 h14[4][K][16];
    __shared__ float  cs[4][64];

    const int tid = threadIdx.x;
    const int w   = tid >> 6;
    const int t   = tid & 63;
    const int qi  = blockIdx.x * 4 + w;
    const int b   = qi >> 12;
    const int i   = qi & (N - 1);
    const float* Fb = F + (size_t)b * N * C;

    float ct = Fb[(size_t)i * C + t];
    cs[w][t] = ct;

    int ids[K];
    const int* kp = knn + (size_t)qi * K;
    #pragma unroll
    for (int k = 0; k < K; k++) ids[k] = kp[k];

    #pragma unroll
    for (int k = 0; k < K; k++) {
        float v = Fb[(size_t)ids[k] * C + t];
        ((float*)&nd4[w][k][0])[t] = v - ct;
    }
    __syncthreads();

    float s0a = b1[t], s0b = 0.f, s0c = 0.f, s0d = 0.f;
    for (int c = 0; c < C; c += 4) {
        s0a = fmaf(cs[w][c + 0], W1[(c + 0) * D + t], s0a);
        s0b = fmaf(cs[w][c + 1], W1[(c + 1) * D + t], s0b);
        s0c = fmaf(cs[w][c + 2], W1[(c + 2) * D + t], s0c);
        s0d = fmaf(cs[w][c + 3], W1[(c + 3) * D + t], s0d);
    }
    float s0 = (s0a + s0b) + (s0c + s0d);

    float acc[K];
    #pragma unroll
    for (int k = 0; k < K; k++) acc[k] = s0;

    for (int c4 = 0; c4 < 16; c4++) {
        float wa = W1[(C + c4 * 4 + 0) * D + t];
        float wb = W1[(C + c4 * 4 + 1) * D + t];
        float wc = W1[(C + c4 * 4 + 2) * D + t];
        float wd = W1[(C + c4 * 4 + 3) * D + t];
        #pragma unroll
        for (int k = 0; k < K; k++) {
            float4 nv = nd4[w][k][c4];
            acc[k] = fmaf(nv.x, wa, acc[k]);
            acc[k] = fmaf(nv.y, wb, acc[k]);
            acc[k] = fmaf(nv.z, wc, acc[k]);
            acc[k] = fmaf(nv.w, wd, acc[k]);
        }
    }
    #pragma unroll
    for (int k = 0; k < K; k++) {
        ((float*)&h14[w][k][0])[t] = gelu_exact(acc[k]);
    }
    __syncthreads();

    float acc2[K];
    float bb = b2[t];
    #pragma unroll
    for (int k = 0; k < K; k++) acc2[k] = bb;
    for (int c4 = 0; c4 < 16; c4++) {
        float wa = W2[(c4 * 4 + 0) * D + t];
        float wb = W2[(c4 * 4 + 1) * D + t];
        float wc = W2[(c4 * 4 + 2) * D + t];
        float wd = W2[(c4 * 4 + 3) * D + t];
        #pragma unroll
        for (int k = 0; k < K; k++) {
            float4 hv = h14[w][k][c4];
            acc2[k] = fmaf(hv.x, wa, acc2[k]);
            acc2[k] = fmaf(hv.y, wb, acc2[k]);
            acc2[k] = fmaf(hv.z, wc, acc2[k]);
            acc2[k] = fmaf(hv.w, wd, acc2[k]);
        }
    }
    float m = -INFINITY;
    #pragma unroll
    for (int k = 0; k < K; k++) m = fmaxf(m, gelu_exact(acc2[k]));

    out[(size_t)qi * D + t] = m;
}

// ---------------------------------------------------------------------------
extern "C" void kernel_launch(void* const* d_in, const int* in_sizes, int n_in,
                              void* d_out, int out_size, void* d_ws, size_t ws_size,
                              hipStream_t stream) {
    const float* F  = (const float*)d_in[0];
    const float* W1 = (const float*)d_in[1];
    const float* b1 = (const float*)d_in[2];
    const float* W2 = (const float*)d_in[3];
    const float* b2 = (const float*)d_in[4];
    float* out = (float*)d_out;

    char* ws = (char*)d_ws;
    float*          sq  = (float*)ws;                             // 128 KB
    int*            knn = (int*)(ws + (128 << 10));               // 2 MB
    unsigned short* HP  = (unsigned short*)(ws + (2176 << 10));   // 4 MB
    unsigned short* MP  = (unsigned short*)(ws + (6272 << 10));   // 4 MB
    unsigned short* LP  = (unsigned short*)(ws + (10368 << 10));  // 4 MB

    prep_kernel<<<dim3(B * N / 256), 256, 0, stream>>>(F, sq, HP, MP, LP);
    knn_mfma_kernel<<<dim3(N / 64, B), 256, 0, stream>>>(HP, MP, LP, sq, knn);
    edgeconv_mlp_kernel<<<dim3(B * N / 4), 256, 0, stream>>>(F, knn, W1, b1, W2, b2, out);
}

// Round 8
// 310.081 us; speedup vs baseline: 2.5251x; 1.2446x over previous
//
#include <hip/hip_runtime.h>
#include <math.h>
#include <stdint.h>

#define B 8
#define N 4096
#define C 64
#define D 64
#define K 16

typedef __attribute__((ext_vector_type(8))) short short8;
typedef __attribute__((ext_vector_type(4))) float f32x4;

// ---------------------------------------------------------------------------
// bf16 helpers
// ---------------------------------------------------------------------------
__device__ __forceinline__ unsigned short f2bf(float x) {
    unsigned u = __float_as_uint(x);
    unsigned r = (u + 0x7FFFu + ((u >> 16) & 1u)) >> 16;   // RNE
    return (unsigned short)r;
}
__device__ __forceinline__ float bf2f(unsigned short h) {
    return __uint_as_float(((unsigned)h) << 16);
}

// key = (d2bits<<32)|idx reinterpreted as double. d2 finite >=0 -> positive
// finite double -> IEEE ordering == integer ordering (exact tie-break kept).
__device__ __forceinline__ double pack_key(float d2, unsigned idx) {
    uint2 u; u.x = idx; u.y = __float_as_uint(d2);
    return __builtin_bit_cast(double, u);
}

// ---------------------------------------------------------------------------
// Kernel 0: per-row sqnorm (round-1 arithmetic, passed) + 3-term bf16 split
// ---------------------------------------------------------------------------
__global__ __launch_bounds__(256)
void prep_kernel(const float* __restrict__ F, float* __restrict__ sq,
                 unsigned short* __restrict__ HP, unsigned short* __restrict__ MP,
                 unsigned short* __restrict__ LP) {
    const int row = blockIdx.x * 256 + threadIdx.x;
    const float4* src = (const float4*)(F + (size_t)row * C);
    float4 v[16];
    #pragma unroll
    for (int q = 0; q < 16; q++) v[q] = src[q];

    {
        float r[8];
        #pragma unroll
        for (int j = 0; j < 8; j++) {
            float t = ((const float*)v)[j];
            r[j] = t * t;
        }
        #pragma unroll
        for (int m = 1; m < 8; m++) {
            #pragma unroll
            for (int j = 0; j < 8; j++) {
                float t = ((const float*)v)[8 * m + j];
                r[j] = fmaf(t, t, r[j]);
            }
        }
        sq[row] = ((r[0] + r[1]) + (r[2] + r[3])) + ((r[4] + r[5]) + (r[6] + r[7]));
    }

    uint4* dh = (uint4*)(HP + (size_t)row * C);
    uint4* dm = (uint4*)(MP + (size_t)row * C);
    uint4* dl = (uint4*)(LP + (size_t)row * C);
    #pragma unroll
    for (int c8 = 0; c8 < 8; c8++) {
        unsigned hq[4], mq[4], lq[4];
        #pragma unroll
        for (int e = 0; e < 4; e++) {
            float x0 = ((const float*)v)[c8 * 8 + 2 * e];
            float x1 = ((const float*)v)[c8 * 8 + 2 * e + 1];
            unsigned short h0 = f2bf(x0), h1 = f2bf(x1);
            float r10 = x0 - bf2f(h0), r11 = x1 - bf2f(h1);
            unsigned short m0 = f2bf(r10), m1 = f2bf(r11);
            float r20 = r10 - bf2f(m0), r21 = r11 - bf2f(m1);
            unsigned short l0 = f2bf(r20), l1 = f2bf(r21);
            hq[e] = (unsigned)h0 | ((unsigned)h1 << 16);
            mq[e] = (unsigned)m0 | ((unsigned)m1 << 16);
            lq[e] = (unsigned)l0 | ((unsigned)l1 << 16);
        }
        dh[c8] = make_uint4(hq[0], hq[1], hq[2], hq[3]);
        dm[c8] = make_uint4(mq[0], mq[1], mq[2], mq[3]);
        dl[c8] = make_uint4(lq[0], lq[1], lq[2], lq[3]);
    }
}

// ---------------------------------------------------------------------------
// Kernel 1: MFMA KNN (round-7, unchanged — passed at ~150us)
// ---------------------------------------------------------------------------
__global__ __launch_bounds__(256)
void knn_mfma_kernel(const unsigned short* __restrict__ HP,
                     const unsigned short* __restrict__ MP,
                     const unsigned short* __restrict__ LP,
                     const float* __restrict__ sqg, int* __restrict__ knn) {
    __shared__ __align__(16) char lds[49152];   // buf0 = [0,24K), buf1 = [24K,48K)

    const int b  = blockIdx.y;
    const int i0 = blockIdx.x * 64;
    const unsigned short* Hb = HP + (size_t)b * N * C;
    const unsigned short* Mb = MP + (size_t)b * N * C;
    const unsigned short* Lb = LP + (size_t)b * N * C;
    const float* sqb = sqg + (size_t)b * N;

    const int tid = threadIdx.x;
    const int l   = tid & 63;
    const int w   = tid >> 6;

    const int lr  = tid >> 2;
    const int lq  = tid & 3;
    const int swzW = (lr & 7) << 4;
    const int wb0 = (lr * 128 + lq * 32) ^ swzW;
    const int wb1 = (lr * 128 + lq * 32 + 16) ^ swzW;

    const double KMAX = __builtin_bit_cast(double, 0x7FEFFFFFFFFFFFFFull);

    uint4 ph0, ph1, pm0, pm1, pl0, pl1;
    {
        const size_t rb = (size_t)lr * C + lq * 16;
        const uint4* sh = (const uint4*)(Hb + rb);
        const uint4* sm = (const uint4*)(Mb + rb);
        const uint4* sl = (const uint4*)(Lb + rb);
        ph0 = sh[0]; ph1 = sh[1]; pm0 = sm[0]; pm1 = sm[1]; pl0 = sl[0]; pl1 = sl[1];
    }

    {   // stage Q planes into buf0
        const uint4* sh = (const uint4*)(Hb + (size_t)(i0 + lr) * C + lq * 16);
        const uint4* sm = (const uint4*)(Mb + (size_t)(i0 + lr) * C + lq * 16);
        const uint4* sl = (const uint4*)(Lb + (size_t)(i0 + lr) * C + lq * 16);
        uint4 a0 = sh[0], a1 = sh[1], m0 = sm[0], m1 = sm[1], e0 = sl[0], e1 = sl[1];
        *(uint4*)(lds +         wb0) = a0; *(uint4*)(lds +         wb1) = a1;
        *(uint4*)(lds +  8192 + wb0) = m0; *(uint4*)(lds +  8192 + wb1) = m1;
        *(uint4*)(lds + 16384 + wb0) = e0; *(uint4*)(lds + 16384 + wb1) = e1;
    }
    __syncthreads();

    const int koff = (l >> 4) * 16;
    const int swzR = (l & 7) << 4;
    const int qrow = w * 16 + (l & 15);
    const int qb0 = (qrow * 128 + koff) ^ swzR;
    const int qb1 = (qrow * 128 + 64 + koff) ^ swzR;
    short8 bh0 = *(const short8*)(lds + qb0),         bh1 = *(const short8*)(lds + qb1);
    short8 bm0 = *(const short8*)(lds +  8192 + qb0), bm1 = *(const short8*)(lds +  8192 + qb1);
    short8 bl0 = *(const short8*)(lds + 16384 + qb0), bl1 = *(const short8*)(lds + 16384 + qb1);

    const float sqq   = sqb[i0 + qrow];
    const int   qglob = i0 + qrow;
    const int   crow0 = (l >> 4) * 4;

    __syncthreads();

    *(uint4*)(lds +         wb0) = ph0; *(uint4*)(lds +         wb1) = ph1;
    *(uint4*)(lds +  8192 + wb0) = pm0; *(uint4*)(lds +  8192 + wb1) = pm1;
    *(uint4*)(lds + 16384 + wb0) = pl0; *(uint4*)(lds + 16384 + wb1) = pl1;

    {
        const size_t rb = (size_t)(64 + lr) * C + lq * 16;
        const uint4* sh = (const uint4*)(Hb + rb);
        const uint4* sm = (const uint4*)(Mb + rb);
        const uint4* sl = (const uint4*)(Lb + rb);
        ph0 = sh[0]; ph1 = sh[1]; pm0 = sm[0]; pm1 = sm[1]; pl0 = sl[0]; pl1 = sl[1];
    }
    __syncthreads();

    double bd[16];
    #pragma unroll
    for (int k = 0; k < 16; k++) bd[k] = KMAX;

    for (int t = 0; t < 64; t++) {
        const int j0 = t * 64;
        char* bufA = lds + ((t & 1) ? 24576 : 0);
        char* bufB = lds + ((t & 1) ? 0 : 24576);

        if (t < 63) {
            *(uint4*)(bufB +         wb0) = ph0; *(uint4*)(bufB +         wb1) = ph1;
            *(uint4*)(bufB +  8192 + wb0) = pm0; *(uint4*)(bufB +  8192 + wb1) = pm1;
            *(uint4*)(bufB + 16384 + wb0) = pl0; *(uint4*)(bufB + 16384 + wb1) = pl1;
        }
        if (t < 62) {
            const size_t rb = (size_t)(j0 + 128 + lr) * C + lq * 16;
            const uint4* sh = (const uint4*)(Hb + rb);
            const uint4* sm = (const uint4*)(Mb + rb);
            const uint4* sl = (const uint4*)(Lb + rb);
            ph0 = sh[0]; ph1 = sh[1]; pm0 = sm[0]; pm1 = sm[1]; pl0 = sl[0]; pl1 = sl[1];
        }

        float4 sqm0 = *(const float4*)(sqb + j0 +      crow0);
        float4 sqm1 = *(const float4*)(sqb + j0 + 16 + crow0);
        float4 sqm2 = *(const float4*)(sqb + j0 + 32 + crow0);
        float4 sqm3 = *(const float4*)(sqb + j0 + 48 + crow0);

        double nk[16];

        #pragma unroll
        for (int m = 0; m < 4; m++) {
            const int arow = m * 16 + (l & 15);
            const int ab0 = (arow * 128 + koff) ^ swzR;
            const int ab1 = (arow * 128 + 64 + koff) ^ swzR;
            short8 ah0 = *(const short8*)(bufA + ab0);
            short8 ah1 = *(const short8*)(bufA + ab1);
            short8 am0 = *(const short8*)(bufA + 8192 + ab0);
            short8 am1 = *(const short8*)(bufA + 8192 + ab1);
            short8 al0 = *(const short8*)(bufA + 16384 + ab0);
            short8 al1 = *(const short8*)(bufA + 16384 + ab1);

            f32x4 acc1 = {0.f, 0.f, 0.f, 0.f};
            acc1 = __builtin_amdgcn_mfma_f32_16x16x32_bf16(am0, bm0, acc1, 0, 0, 0);
            acc1 = __builtin_amdgcn_mfma_f32_16x16x32_bf16(am1, bm1, acc1, 0, 0, 0);
            acc1 = __builtin_amdgcn_mfma_f32_16x16x32_bf16(ah0, bl0, acc1, 0, 0, 0);
            acc1 = __builtin_amdgcn_mfma_f32_16x16x32_bf16(ah1, bl1, acc1, 0, 0, 0);
            acc1 = __builtin_amdgcn_mfma_f32_16x16x32_bf16(al0, bh0, acc1, 0, 0, 0);
            f32x4 acc2 = {0.f, 0.f, 0.f, 0.f};
            acc2 = __builtin_amdgcn_mfma_f32_16x16x32_bf16(al1, bh1, acc2, 0, 0, 0);
            acc2 = __builtin_amdgcn_mfma_f32_16x16x32_bf16(ah0, bm0, acc2, 0, 0, 0);
            acc2 = __builtin_amdgcn_mfma_f32_16x16x32_bf16(ah1, bm1, acc2, 0, 0, 0);
            acc2 = __builtin_amdgcn_mfma_f32_16x16x32_bf16(am0, bh0, acc2, 0, 0, 0);
            acc2 = __builtin_amdgcn_mfma_f32_16x16x32_bf16(am1, bh1, acc2, 0, 0, 0);
            f32x4 acch = {0.f, 0.f, 0.f, 0.f};
            acch = __builtin_amdgcn_mfma_f32_16x16x32_bf16(ah0, bh0, acch, 0, 0, 0);
            acch = __builtin_amdgcn_mfma_f32_16x16x32_bf16(ah1, bh1, acch, 0, 0, 0);

            float4 sqm = (m == 0) ? sqm0 : (m == 1) ? sqm1 : (m == 2) ? sqm2 : sqm3;
            #pragma unroll
            for (int r = 0; r < 4; r++) {
                float sqc = (r == 0) ? sqm.x : (r == 1) ? sqm.y : (r == 2) ? sqm.z : sqm.w;
                float gg = acch[r] + (acc1[r] + acc2[r]);
                float d2 = fmaf(-2.0f, gg, sqq + sqc);
                d2 = fmaxf(d2, 0.0f);
                nk[m * 4 + r] = pack_key(d2, (unsigned)(j0 + m * 16 + crow0 + r));
            }
        }

        if (j0 == i0) {
            #pragma unroll
            for (int m = 0; m < 4; m++)
                #pragma unroll
                for (int r = 0; r < 4; r++)
                    if ((j0 + m * 16 + crow0 + r) == qglob) nk[m * 4 + r] = KMAX;
        }

        #pragma unroll
        for (int kk = 2; kk <= 16; kk <<= 1) {
            #pragma unroll
            for (int j = kk >> 1; j > 0; j >>= 1) {
                #pragma unroll
                for (int i = 0; i < 16; i++) {
                    int ixj = i ^ j;
                    if (ixj > i) {
                        bool asc = ((i & kk) != 0);
                        double a = nk[i], c = nk[ixj];
                        nk[i]   = asc ? fmin(a, c) : fmax(a, c);
                        nk[ixj] = asc ? fmax(a, c) : fmin(a, c);
                    }
                }
            }
        }
        #pragma unroll
        for (int i = 0; i < 16; i++) bd[i] = fmin(bd[i], nk[i]);
        #pragma unroll
        for (int j = 8; j > 0; j >>= 1) {
            #pragma unroll
            for (int i = 0; i < 16; i++) {
                int ixj = i ^ j;
                if (ixj > i) {
                    double a = bd[i], c = bd[ixj];
                    bd[i]   = fmin(a, c);
                    bd[ixj] = fmax(a, c);
                }
            }
        }

        __syncthreads();
    }

    uint64_t* keys = (uint64_t*)lds;
    {
        const int qloc = w * 16 + (l & 15);
        const int sl2  = l >> 4;
        const int base = (qloc * 4 + sl2) * 16;
        #pragma unroll
        for (int k = 0; k < 16; k++)
            keys[base + k] = __builtin_bit_cast(uint64_t, bd[k]);
    }
    __syncthreads();
    if (tid < 64) {
        const uint64_t* K0 = keys + (tid * 4 + 0) * 16;
        const uint64_t* K1 = keys + (tid * 4 + 1) * 16;
        const uint64_t* K2 = keys + (tid * 4 + 2) * 16;
        const uint64_t* K3 = keys + (tid * 4 + 3) * 16;
        int p0 = 0, p1 = 0, p2 = 0, p3 = 0;
        uint64_t h0 = K0[0], h1 = K1[0], h2 = K2[0], h3 = K3[0];
        int* dst = knn + ((size_t)b * N + i0 + tid) * K;
        #pragma unroll
        for (int k = 0; k < K; k++) {
            uint64_t m01 = h0 < h1 ? h0 : h1;
            uint64_t m23 = h2 < h3 ? h2 : h3;
            uint64_t mv  = m01 < m23 ? m01 : m23;
            dst[k] = (int)(mv & 0xFFFFFFFFu);
            if      (mv == h0) { ++p0; h0 = (p0 < 16) ? K0[p0] : ~0ull; }
            else if (mv == h1) { ++p1; h1 = (p1 < 16) ? K1[p1] : ~0ull; }
            else if (mv == h2) { ++p2; h2 = (p2 < 16) ? K2[p2] : ~0ull; }
            else               { ++p3; h3 = (p3 < 16) ? K3[p3] : ~0ull; }
        }
    }
}

// ---------------------------------------------------------------------------
// Kernel 2: MFMA MLP. One wave per query (4 queries sequentially per wave).
// A = 16x128 edge rows [diff | central] hi/m split; W1 pre-transposed+swizzled
// in LDS; W2 fragments in registers. h transposed through per-wave LDS.
// ---------------------------------------------------------------------------
__device__ __forceinline__ float gelu_exact(float x) {
    return 0.5f * x * (1.0f + erff(x * 0.70710678118654752440f));
}

#define QPW 4

__global__ __launch_bounds__(256)
void mlp_mfma_kernel(const float* __restrict__ F,
                     const unsigned short* __restrict__ HP,
                     const unsigned short* __restrict__ MP,
                     const int* __restrict__ knn,
                     const float* __restrict__ W1, const float* __restrict__ b1,
                     const float* __restrict__ W2, const float* __restrict__ b2,
                     float* __restrict__ out) {
    // W1Tp[n][k] = W1[(k<64 ? 64+k : k-64)][n] ; rows 256B, XOR ((n&15)<<4)
    __shared__ __align__(16) unsigned short W1h[64 * 128];   // 16KB
    __shared__ __align__(16) unsigned short W1m[64 * 128];   // 16KB
    __shared__ __align__(16) unsigned short hbh[4][1024];    // per-wave h hi [16][64]
    __shared__ __align__(16) unsigned short hbm[4][1024];    // per-wave h mid

    const int tid = threadIdx.x;
    const int l   = tid & 63;
    const int w   = tid >> 6;

    // ---- stage W1 transposed+split (coalesced reads over n) ----
    for (int e = tid; e < 8192; e += 256) {
        const int n = e & 63, k = e >> 6;
        const int srcrow = (k < 64) ? (64 + k) : (k - 64);
        float x = W1[srcrow * 64 + n];
        unsigned short hh = f2bf(x);
        unsigned short mm = f2bf(x - bf2f(hh));
        const int byte = (n * 256 + k * 2) ^ ((n & 15) << 4);
        *(unsigned short*)((char*)W1h + byte) = hh;
        *(unsigned short*)((char*)W1m + byte) = mm;
    }

    // ---- W2 fragments in registers: B2[nt][kc] = W2T[n][k] split ----
    short8 B2h[4][2], B2m[4][2];
    float b1v[4], b2v[4];
    {
        const int n = (l & 15);
        #pragma unroll
        for (int nt = 0; nt < 4; nt++) {
            const int nn = nt * 16 + n;
            b1v[nt] = b1[nn];
            b2v[nt] = b2[nn];
            #pragma unroll
            for (int c = 0; c < 2; c++) {
                const int k0 = c * 32 + (l >> 4) * 8;
                short8 vh, vm;
                #pragma unroll
                for (int jj = 0; jj < 8; jj++) {
                    float x = W2[(k0 + jj) * 64 + nn];
                    unsigned short hh = f2bf(x);
                    vh[jj] = (short)hh;
                    vm[jj] = (short)f2bf(x - bf2f(hh));
                }
                B2h[nt][c] = vh; B2m[nt][c] = vm;
            }
        }
    }
    __syncthreads();

    const int cb   = (l >> 4) * 8;                  // lane's channel base
    const int swzL = (l & 15) << 4;                 // W1 read swizzle (n&15 == l&15)

    for (int jq = 0; jq < QPW; jq++) {
        const int q  = (blockIdx.x * 4 + w) * QPW + jq;
        const int b  = q >> 12;
        const int ci = q & (N - 1);
        const float*          Fb  = F  + (size_t)b * N * C;
        const unsigned short* HPb = HP + (size_t)b * N * C;
        const unsigned short* MPb = MP + (size_t)b * N * C;

        const int nb = knn[(size_t)q * K + (l & 15)];    // this lane's neighbor row

        // central fp32 (for diff) + central bf16 frags from planes
        float4 cA0 = *(const float4*)(Fb + (size_t)ci * C + cb);
        float4 cA1 = *(const float4*)(Fb + (size_t)ci * C + cb + 4);
        float4 cB0 = *(const float4*)(Fb + (size_t)ci * C + 32 + cb);
        float4 cB1 = *(const float4*)(Fb + (size_t)ci * C + 36 + cb);
        float4 nA0 = *(const float4*)(Fb + (size_t)nb * C + cb);
        float4 nA1 = *(const float4*)(Fb + (size_t)nb * C + cb + 4);
        float4 nB0 = *(const float4*)(Fb + (size_t)nb * C + 32 + cb);
        float4 nB1 = *(const float4*)(Fb + (size_t)nb * C + 36 + cb);

        short8 ach0 = *(const short8*)(HPb + (size_t)ci * C + cb);
        short8 ach1 = *(const short8*)(HPb + (size_t)ci * C + 32 + cb);
        short8 acm0 = *(const short8*)(MPb + (size_t)ci * C + cb);
        short8 acm1 = *(const short8*)(MPb + (size_t)ci * C + 32 + cb);

        // diff split -> A frags chunks 0,1
        short8 adh0, adm0, adh1, adm1;
        {
            float d0[8] = {nA0.x - cA0.x, nA0.y - cA0.y, nA0.z - cA0.z, nA0.w - cA0.w,
                           nA1.x - cA1.x, nA1.y - cA1.y, nA1.z - cA1.z, nA1.w - cA1.w};
            float d1[8] = {nB0.x - cB0.x, nB0.y - cB0.y, nB0.z - cB0.z, nB0.w - cB0.w,
                           nB1.x - cB1.x, nB1.y - cB1.y, nB1.z - cB1.z, nB1.w - cB1.w};
            #pragma unroll
            for (int jj = 0; jj < 8; jj++) {
                unsigned short h0 = f2bf(d0[jj]);
                adh0[jj] = (short)h0; adm0[jj] = (short)f2bf(d0[jj] - bf2f(h0));
                unsigned short h1 = f2bf(d1[jj]);
                adh1[jj] = (short)h1; adm1[jj] = (short)f2bf(d1[jj] - bf2f(h1));
            }
        }

        // ---- layer 1: 4 col-tiles, K=128 (chunks: 0,1 diff; 2,3 central) ----
        #pragma unroll
        for (int nt = 0; nt < 4; nt++) {
            const int rowb = (nt * 16 + (l & 15)) * 256 + (l >> 4) * 16;
            f32x4 a1 = {0.f, 0.f, 0.f, 0.f};
            f32x4 a2 = {0.f, 0.f, 0.f, 0.f};
            #pragma unroll
            for (int kc = 0; kc < 4; kc++) {
                const int byte = (rowb + kc * 64) ^ swzL;
                short8 Bh = *(const short8*)((char*)W1h + byte);
                short8 Bm = *(const short8*)((char*)W1m + byte);
                short8 Ah = (kc == 0) ? adh0 : (kc == 1) ? adh1 : (kc == 2) ? ach0 : ach1;
                short8 Am = (kc == 0) ? adm0 : (kc == 1) ? adm1 : (kc == 2) ? acm0 : acm1;
                a1 = __builtin_amdgcn_mfma_f32_16x16x32_bf16(Ah, Bh, a1, 0, 0, 0);
                a2 = __builtin_amdgcn_mfma_f32_16x16x32_bf16(Ah, Bm, a2, 0, 0, 0);
                a2 = __builtin_amdgcn_mfma_f32_16x16x32_bf16(Am, Bh, a2, 0, 0, 0);
            }
            // gelu + split + transpose-store (row = neighbor, col = channel)
            #pragma unroll
            for (int r = 0; r < 4; r++) {
                const int row = (l >> 4) * 4 + r;
                const int col = nt * 16 + (l & 15);
                float hv = gelu_exact(a1[r] + a2[r] + b1v[nt]);
                unsigned short hh = f2bf(hv);
                unsigned short hm = f2bf(hv - bf2f(hh));
                const int byte = (row * 128 + col * 2) ^ ((row & 7) << 4);
                *(unsigned short*)((char*)&hbh[w][0] + byte) = hh;
                *(unsigned short*)((char*)&hbm[w][0] + byte) = hm;
            }
        }

        asm volatile("s_waitcnt lgkmcnt(0)" ::: "memory");
        __builtin_amdgcn_sched_barrier(0);

        // ---- layer 2: A = h rows, B = W2 register frags ----
        short8 Ah2[2], Am2[2];
        #pragma unroll
        for (int kc = 0; kc < 2; kc++) {
            const int byte = ((l & 15) * 128 + kc * 64 + (l >> 4) * 16) ^ (((l & 15) & 7) << 4);
            Ah2[kc] = *(const short8*)((char*)&hbh[w][0] + byte);
            Am2[kc] = *(const short8*)((char*)&hbm[w][0] + byte);
        }
        #pragma unroll
        for (int nt = 0; nt < 4; nt++) {
            f32x4 a1 = {0.f, 0.f, 0.f, 0.f};
            f32x4 a2 = {0.f, 0.f, 0.f, 0.f};
            #pragma unroll
            for (int kc = 0; kc < 2; kc++) {
                a1 = __builtin_amdgcn_mfma_f32_16x16x32_bf16(Ah2[kc], B2h[nt][kc], a1, 0, 0, 0);
                a2 = __builtin_amdgcn_mfma_f32_16x16x32_bf16(Ah2[kc], B2m[nt][kc], a2, 0, 0, 0);
                a2 = __builtin_amdgcn_mfma_f32_16x16x32_bf16(Am2[kc], B2h[nt][kc], a2, 0, 0, 0);
            }
            float mx = -INFINITY;
            #pragma unroll
            for (int r = 0; r < 4; r++)
                mx = fmaxf(mx, gelu_exact(a1[r] + a2[r] + b2v[nt]));
            mx = fmaxf(mx, __shfl_xor(mx, 16));
            mx = fmaxf(mx, __shfl_xor(mx, 32));
            if (l < 16) out[(size_t)q * D + nt * 16 + l] = mx;
        }
    }
}

// ---------------------------------------------------------------------------
extern "C" void kernel_launch(void* const* d_in, const int* in_sizes, int n_in,
                              void* d_out, int out_size, void* d_ws, size_t ws_size,
                              hipStream_t stream) {
    const float* F  = (const float*)d_in[0];
    const float* W1 = (const float*)d_in[1];
    const float* b1 = (const float*)d_in[2];
    const float* W2 = (const float*)d_in[3];
    const float* b2 = (const float*)d_in[4];
    float* out = (float*)d_out;

    char* ws = (char*)d_ws;
    float*          sq  = (float*)ws;                             // 128 KB
    int*            knn = (int*)(ws + (128 << 10));               // 2 MB
    unsigned short* HP  = (unsigned short*)(ws + (2176 << 10));   // 4 MB
    unsigned short* MP  = (unsigned short*)(ws + (6272 << 10));   // 4 MB
    unsigned short* LP  = (unsigned short*)(ws + (10368 << 10));  // 4 MB

    prep_kernel<<<dim3(B * N / 256), 256, 0, stream>>>(F, sq, HP, MP, LP);
    knn_mfma_kernel<<<dim3(N / 64, B), 256, 0, stream>>>(HP, MP, LP, sq, knn);
    mlp_mfma_kernel<<<dim3(B * N / (4 * QPW)), 256, 0, stream>>>(
        F, HP, MP, knn, W1, b1, W2, b2, out);
}

// Round 9
// 301.958 us; speedup vs baseline: 2.5930x; 1.0269x over previous
//
#include <hip/hip_runtime.h>
#include <math.h>
#include <stdint.h>

#define B 8
#define N 4096
#define C 64
#define D 64
#define K 16

typedef __attribute__((ext_vector_type(8))) short short8;
typedef __attribute__((ext_vector_type(4))) float f32x4;

// ---------------------------------------------------------------------------
// bf16 helpers
// ---------------------------------------------------------------------------
__device__ __forceinline__ unsigned short f2bf(float x) {
    unsigned u = __float_as_uint(x);
    unsigned r = (u + 0x7FFFu + ((u >> 16) & 1u)) >> 16;   // RNE
    return (unsigned short)r;
}
__device__ __forceinline__ float bf2f(unsigned short h) {
    return __uint_as_float(((unsigned)h) << 16);
}

// key = (d2bits<<32)|idx reinterpreted as double. d2 finite >=0 -> positive
// finite double -> IEEE ordering == integer ordering (exact tie-break kept).
__device__ __forceinline__ double pack_key(float d2, unsigned idx) {
    uint2 u; u.x = idx; u.y = __float_as_uint(d2);
    return __builtin_bit_cast(double, u);
}

// ---------------------------------------------------------------------------
// Kernel 0: per-row sqnorm (round-1 arithmetic, passed) + 3-term bf16 split
// ---------------------------------------------------------------------------
__global__ __launch_bounds__(256)
void prep_kernel(const float* __restrict__ F, float* __restrict__ sq,
                 unsigned short* __restrict__ HP, unsigned short* __restrict__ MP,
                 unsigned short* __restrict__ LP) {
    const int row = blockIdx.x * 256 + threadIdx.x;
    const float4* src = (const float4*)(F + (size_t)row * C);
    float4 v[16];
    #pragma unroll
    for (int q = 0; q < 16; q++) v[q] = src[q];

    {
        float r[8];
        #pragma unroll
        for (int j = 0; j < 8; j++) {
            float t = ((const float*)v)[j];
            r[j] = t * t;
        }
        #pragma unroll
        for (int m = 1; m < 8; m++) {
            #pragma unroll
            for (int j = 0; j < 8; j++) {
                float t = ((const float*)v)[8 * m + j];
                r[j] = fmaf(t, t, r[j]);
            }
        }
        sq[row] = ((r[0] + r[1]) + (r[2] + r[3])) + ((r[4] + r[5]) + (r[6] + r[7]));
    }

    uint4* dh = (uint4*)(HP + (size_t)row * C);
    uint4* dm = (uint4*)(MP + (size_t)row * C);
    uint4* dl = (uint4*)(LP + (size_t)row * C);
    #pragma unroll
    for (int c8 = 0; c8 < 8; c8++) {
        unsigned hq[4], mq[4], lq[4];
        #pragma unroll
        for (int e = 0; e < 4; e++) {
            float x0 = ((const float*)v)[c8 * 8 + 2 * e];
            float x1 = ((const float*)v)[c8 * 8 + 2 * e + 1];
            unsigned short h0 = f2bf(x0), h1 = f2bf(x1);
            float r10 = x0 - bf2f(h0), r11 = x1 - bf2f(h1);
            unsigned short m0 = f2bf(r10), m1 = f2bf(r11);
            float r20 = r10 - bf2f(m0), r21 = r11 - bf2f(m1);
            unsigned short l0 = f2bf(r20), l1 = f2bf(r21);
            hq[e] = (unsigned)h0 | ((unsigned)h1 << 16);
            mq[e] = (unsigned)m0 | ((unsigned)m1 << 16);
            lq[e] = (unsigned)l0 | ((unsigned)l1 << 16);
        }
        dh[c8] = make_uint4(hq[0], hq[1], hq[2], hq[3]);
        dm[c8] = make_uint4(mq[0], mq[1], mq[2], mq[3]);
        dl[c8] = make_uint4(lq[0], lq[1], lq[2], lq[3]);
    }
}

// ---------------------------------------------------------------------------
// Kernel 1: MFMA KNN, split-K x2. Block (x, s, b) = 64 queries x 2048 cands
// (tiles of the s-th half). Round-7-proven engine: dbuf LDS, 3-chain MFMA,
// f64 fmin/fmax bitonic selection. Output: 16 sorted keys/query/half.
// ---------------------------------------------------------------------------
__global__ __launch_bounds__(256)
void knn_mfma_kernel(const unsigned short* __restrict__ HP,
                     const unsigned short* __restrict__ MP,
                     const unsigned short* __restrict__ LP,
                     const float* __restrict__ sqg, uint64_t* __restrict__ keysg) {
    __shared__ __align__(16) char lds[49152];   // buf0 = [0,24K), buf1 = [24K,48K)

    const int s  = blockIdx.y;                  // candidate half
    const int b  = blockIdx.z;
    const int i0 = blockIdx.x * 64;
    const int c0 = s * 2048;
    const unsigned short* Hb = HP + (size_t)b * N * C;
    const unsigned short* Mb = MP + (size_t)b * N * C;
    const unsigned short* Lb = LP + (size_t)b * N * C;
    const float* sqb = sqg + (size_t)b * N;

    const int tid = threadIdx.x;
    const int l   = tid & 63;
    const int w   = tid >> 6;

    const int lr  = tid >> 2;
    const int lq  = tid & 3;
    const int swzW = (lr & 7) << 4;
    const int wb0 = (lr * 128 + lq * 32) ^ swzW;
    const int wb1 = (lr * 128 + lq * 32 + 16) ^ swzW;

    const double KMAX = __builtin_bit_cast(double, 0x7FEFFFFFFFFFFFFFull);

    // prefetch first tile of this half (hides under Q staging)
    uint4 ph0, ph1, pm0, pm1, pl0, pl1;
    {
        const size_t rb = (size_t)(c0 + lr) * C + lq * 16;
        const uint4* sh = (const uint4*)(Hb + rb);
        const uint4* sm = (const uint4*)(Mb + rb);
        const uint4* sl = (const uint4*)(Lb + rb);
        ph0 = sh[0]; ph1 = sh[1]; pm0 = sm[0]; pm1 = sm[1]; pl0 = sl[0]; pl1 = sl[1];
    }

    {   // stage Q planes into buf0
        const uint4* sh = (const uint4*)(Hb + (size_t)(i0 + lr) * C + lq * 16);
        const uint4* sm = (const uint4*)(Mb + (size_t)(i0 + lr) * C + lq * 16);
        const uint4* sl = (const uint4*)(Lb + (size_t)(i0 + lr) * C + lq * 16);
        uint4 a0 = sh[0], a1 = sh[1], m0 = sm[0], m1 = sm[1], e0 = sl[0], e1 = sl[1];
        *(uint4*)(lds +         wb0) = a0; *(uint4*)(lds +         wb1) = a1;
        *(uint4*)(lds +  8192 + wb0) = m0; *(uint4*)(lds +  8192 + wb1) = m1;
        *(uint4*)(lds + 16384 + wb0) = e0; *(uint4*)(lds + 16384 + wb1) = e1;
    }
    __syncthreads();

    // B fragments (query), register-resident for the whole scan
    const int koff = (l >> 4) * 16;
    const int swzR = (l & 7) << 4;
    const int qrow = w * 16 + (l & 15);
    const int qb0 = (qrow * 128 + koff) ^ swzR;
    const int qb1 = (qrow * 128 + 64 + koff) ^ swzR;
    short8 bh0 = *(const short8*)(lds + qb0),         bh1 = *(const short8*)(lds + qb1);
    short8 bm0 = *(const short8*)(lds +  8192 + qb0), bm1 = *(const short8*)(lds +  8192 + qb1);
    short8 bl0 = *(const short8*)(lds + 16384 + qb0), bl1 = *(const short8*)(lds + 16384 + qb1);

    const float sqq   = sqb[i0 + qrow];
    const int   qglob = i0 + qrow;
    const int   crow0 = (l >> 4) * 4;

    __syncthreads();          // all waves finished reading Q from buf0

    // stage first tile into buf0 (overwrites Q region)
    *(uint4*)(lds +         wb0) = ph0; *(uint4*)(lds +         wb1) = ph1;
    *(uint4*)(lds +  8192 + wb0) = pm0; *(uint4*)(lds +  8192 + wb1) = pm1;
    *(uint4*)(lds + 16384 + wb0) = pl0; *(uint4*)(lds + 16384 + wb1) = pl1;

    {   // prefetch second tile
        const size_t rb = (size_t)(c0 + 64 + lr) * C + lq * 16;
        const uint4* sh = (const uint4*)(Hb + rb);
        const uint4* sm = (const uint4*)(Mb + rb);
        const uint4* sl = (const uint4*)(Lb + rb);
        ph0 = sh[0]; ph1 = sh[1]; pm0 = sm[0]; pm1 = sm[1]; pl0 = sl[0]; pl1 = sl[1];
    }
    __syncthreads();          // first tile visible

    double bd[16];
    #pragma unroll
    for (int k = 0; k < 16; k++) bd[k] = KMAX;

    for (int t = 0; t < 32; t++) {
        const int j0 = c0 + t * 64;
        char* bufA = lds + ((t & 1) ? 24576 : 0);      // compute tile t
        char* bufB = lds + ((t & 1) ? 0 : 24576);      // stage tile t+1

        if (t < 31) {
            *(uint4*)(bufB +         wb0) = ph0; *(uint4*)(bufB +         wb1) = ph1;
            *(uint4*)(bufB +  8192 + wb0) = pm0; *(uint4*)(bufB +  8192 + wb1) = pm1;
            *(uint4*)(bufB + 16384 + wb0) = pl0; *(uint4*)(bufB + 16384 + wb1) = pl1;
        }
        if (t < 30) {
            const size_t rb = (size_t)(j0 + 128 + lr) * C + lq * 16;
            const uint4* sh = (const uint4*)(Hb + rb);
            const uint4* sm = (const uint4*)(Mb + rb);
            const uint4* sl = (const uint4*)(Lb + rb);
            ph0 = sh[0]; ph1 = sh[1]; pm0 = sm[0]; pm1 = sm[1]; pl0 = sl[0]; pl1 = sl[1];
        }

        float4 sqm0 = *(const float4*)(sqb + j0 +      crow0);
        float4 sqm1 = *(const float4*)(sqb + j0 + 16 + crow0);
        float4 sqm2 = *(const float4*)(sqb + j0 + 32 + crow0);
        float4 sqm3 = *(const float4*)(sqb + j0 + 48 + crow0);

        double nk[16];

        #pragma unroll
        for (int m = 0; m < 4; m++) {
            const int arow = m * 16 + (l & 15);
            const int ab0 = (arow * 128 + koff) ^ swzR;
            const int ab1 = (arow * 128 + 64 + koff) ^ swzR;
            short8 ah0 = *(const short8*)(bufA + ab0);
            short8 ah1 = *(const short8*)(bufA + ab1);
            short8 am0 = *(const short8*)(bufA + 8192 + ab0);
            short8 am1 = *(const short8*)(bufA + 8192 + ab1);
            short8 al0 = *(const short8*)(bufA + 16384 + ab0);
            short8 al1 = *(const short8*)(bufA + 16384 + ab1);

            f32x4 acc1 = {0.f, 0.f, 0.f, 0.f};
            acc1 = __builtin_amdgcn_mfma_f32_16x16x32_bf16(am0, bm0, acc1, 0, 0, 0);
            acc1 = __builtin_amdgcn_mfma_f32_16x16x32_bf16(am1, bm1, acc1, 0, 0, 0);
            acc1 = __builtin_amdgcn_mfma_f32_16x16x32_bf16(ah0, bl0, acc1, 0, 0, 0);
            acc1 = __builtin_amdgcn_mfma_f32_16x16x32_bf16(ah1, bl1, acc1, 0, 0, 0);
            acc1 = __builtin_amdgcn_mfma_f32_16x16x32_bf16(al0, bh0, acc1, 0, 0, 0);
            f32x4 acc2 = {0.f, 0.f, 0.f, 0.f};
            acc2 = __builtin_amdgcn_mfma_f32_16x16x32_bf16(al1, bh1, acc2, 0, 0, 0);
            acc2 = __builtin_amdgcn_mfma_f32_16x16x32_bf16(ah0, bm0, acc2, 0, 0, 0);
            acc2 = __builtin_amdgcn_mfma_f32_16x16x32_bf16(ah1, bm1, acc2, 0, 0, 0);
            acc2 = __builtin_amdgcn_mfma_f32_16x16x32_bf16(am0, bh0, acc2, 0, 0, 0);
            acc2 = __builtin_amdgcn_mfma_f32_16x16x32_bf16(am1, bh1, acc2, 0, 0, 0);
            f32x4 acch = {0.f, 0.f, 0.f, 0.f};
            acch = __builtin_amdgcn_mfma_f32_16x16x32_bf16(ah0, bh0, acch, 0, 0, 0);
            acch = __builtin_amdgcn_mfma_f32_16x16x32_bf16(ah1, bh1, acch, 0, 0, 0);

            float4 sqm = (m == 0) ? sqm0 : (m == 1) ? sqm1 : (m == 2) ? sqm2 : sqm3;
            #pragma unroll
            for (int r = 0; r < 4; r++) {
                float sqc = (r == 0) ? sqm.x : (r == 1) ? sqm.y : (r == 2) ? sqm.z : sqm.w;
                float gg = acch[r] + (acc1[r] + acc2[r]);
                float d2 = fmaf(-2.0f, gg, sqq + sqc);
                d2 = fmaxf(d2, 0.0f);
                nk[m * 4 + r] = pack_key(d2, (unsigned)(j0 + m * 16 + crow0 + r));
            }
        }

        // diagonal tile only: kill self-match (wave-uniform branch)
        if (j0 == i0) {
            #pragma unroll
            for (int m = 0; m < 4; m++)
                #pragma unroll
                for (int r = 0; r < 4; r++)
                    if ((j0 + m * 16 + crow0 + r) == qglob) nk[m * 4 + r] = KMAX;
        }

        // ---- bitonic sort nk DESCENDING via fmin/fmax (2-instr CAS) ----
        #pragma unroll
        for (int kk = 2; kk <= 16; kk <<= 1) {
            #pragma unroll
            for (int j = kk >> 1; j > 0; j >>= 1) {
                #pragma unroll
                for (int i = 0; i < 16; i++) {
                    int ixj = i ^ j;
                    if (ixj > i) {
                        bool asc = ((i & kk) != 0);
                        double a = nk[i], c = nk[ixj];
                        nk[i]   = asc ? fmin(a, c) : fmax(a, c);
                        nk[ixj] = asc ? fmax(a, c) : fmin(a, c);
                    }
                }
            }
        }
        #pragma unroll
        for (int i = 0; i < 16; i++) bd[i] = fmin(bd[i], nk[i]);
        #pragma unroll
        for (int j = 8; j > 0; j >>= 1) {
            #pragma unroll
            for (int i = 0; i < 16; i++) {
                int ixj = i ^ j;
                if (ixj > i) {
                    double a = bd[i], c = bd[ixj];
                    bd[i]   = fmin(a, c);
                    bd[ixj] = fmax(a, c);
                }
            }
        }

        __syncthreads();       // tile t+1 staged & prior reads done
    }

    // ---- merge 4 wave-lists per query -> 16 sorted keys for this half ----
    uint64_t* keys = (uint64_t*)lds;           // 32KB reuse
    {
        const int qloc = w * 16 + (l & 15);
        const int sl2  = l >> 4;
        const int base = (qloc * 4 + sl2) * 16;
        #pragma unroll
        for (int k = 0; k < 16; k++)
            keys[base + k] = __builtin_bit_cast(uint64_t, bd[k]);
    }
    __syncthreads();
    if (tid < 64) {
        const uint64_t* K0 = keys + (tid * 4 + 0) * 16;
        const uint64_t* K1 = keys + (tid * 4 + 1) * 16;
        const uint64_t* K2 = keys + (tid * 4 + 2) * 16;
        const uint64_t* K3 = keys + (tid * 4 + 3) * 16;
        int p0 = 0, p1 = 0, p2 = 0, p3 = 0;
        uint64_t h0 = K0[0], h1 = K1[0], h2 = K2[0], h3 = K3[0];
        uint64_t* dst = keysg + ((size_t)b * N + i0 + tid) * 32 + s * 16;
        #pragma unroll
        for (int k = 0; k < K; k++) {
            uint64_t m01 = h0 < h1 ? h0 : h1;
            uint64_t m23 = h2 < h3 ? h2 : h3;
            uint64_t mv  = m01 < m23 ? m01 : m23;
            dst[k] = mv;
            if      (mv == h0) { ++p0; h0 = (p0 < 16) ? K0[p0] : ~0ull; }
            else if (mv == h1) { ++p1; h1 = (p1 < 16) ? K1[p1] : ~0ull; }
            else if (mv == h2) { ++p2; h2 = (p2 < 16) ? K2[p2] : ~0ull; }
            else               { ++p3; h3 = (p3 < 16) ? K3[p3] : ~0ull; }
        }
    }
}

// ---------------------------------------------------------------------------
// Kernel 1b: final 2-way merge of the two halves, one thread per query
// ---------------------------------------------------------------------------
__global__ __launch_bounds__(256)
void knn_merge_kernel(const uint64_t* __restrict__ keysg, int* __restrict__ knn) {
    const int q = blockIdx.x * 256 + threadIdx.x;     // 0..B*N-1
    const uint64_t* A  = keysg + (size_t)q * 32;
    const uint64_t* Bp = A + 16;
    int pa = 0, pb = 0;
    uint64_t ha = A[0], hb = Bp[0];
    int* dst = knn + (size_t)q * K;
    #pragma unroll
    for (int k = 0; k < K; k++) {
        uint64_t mv = ha < hb ? ha : hb;
        dst[k] = (int)(mv & 0xFFFFFFFFu);
        if (mv == ha) { ++pa; ha = (pa < 16) ? A[pa] : ~0ull; }
        else          { ++pb; hb = (pb < 16) ? Bp[pb] : ~0ull; }
    }
}

// ---------------------------------------------------------------------------
// Kernel 2: MFMA MLP (round-8, unchanged — passed at ~80us)
// ---------------------------------------------------------------------------
__device__ __forceinline__ float gelu_exact(float x) {
    return 0.5f * x * (1.0f + erff(x * 0.70710678118654752440f));
}

#define QPW 4

__global__ __launch_bounds__(256)
void mlp_mfma_kernel(const float* __restrict__ F,
                     const unsigned short* __restrict__ HP,
                     const unsigned short* __restrict__ MP,
                     const int* __restrict__ knn,
                     const float* __restrict__ W1, const float* __restrict__ b1,
                     const float* __restrict__ W2, const float* __restrict__ b2,
                     float* __restrict__ out) {
    __shared__ __align__(16) unsigned short W1h[64 * 128];   // 16KB
    __shared__ __align__(16) unsigned short W1m[64 * 128];   // 16KB
    __shared__ __align__(16) unsigned short hbh[4][1024];
    __shared__ __align__(16) unsigned short hbm[4][1024];

    const int tid = threadIdx.x;
    const int l   = tid & 63;
    const int w   = tid >> 6;

    for (int e = tid; e < 8192; e += 256) {
        const int n = e & 63, k = e >> 6;
        const int srcrow = (k < 64) ? (64 + k) : (k - 64);
        float x = W1[srcrow * 64 + n];
        unsigned short hh = f2bf(x);
        unsigned short mm = f2bf(x - bf2f(hh));
        const int byte = (n * 256 + k * 2) ^ ((n & 15) << 4);
        *(unsigned short*)((char*)W1h + byte) = hh;
        *(unsigned short*)((char*)W1m + byte) = mm;
    }

    short8 B2h[4][2], B2m[4][2];
    float b1v[4], b2v[4];
    {
        const int n = (l & 15);
        #pragma unroll
        for (int nt = 0; nt < 4; nt++) {
            const int nn = nt * 16 + n;
            b1v[nt] = b1[nn];
            b2v[nt] = b2[nn];
            #pragma unroll
            for (int c = 0; c < 2; c++) {
                const int k0 = c * 32 + (l >> 4) * 8;
                short8 vh, vm;
                #pragma unroll
                for (int jj = 0; jj < 8; jj++) {
                    float x = W2[(k0 + jj) * 64 + nn];
                    unsigned short hh = f2bf(x);
                    vh[jj] = (short)hh;
                    vm[jj] = (short)f2bf(x - bf2f(hh));
                }
                B2h[nt][c] = vh; B2m[nt][c] = vm;
            }
        }
    }
    __syncthreads();

    const int cb   = (l >> 4) * 8;
    const int swzL = (l & 15) << 4;

    for (int jq = 0; jq < QPW; jq++) {
        const int q  = (blockIdx.x * 4 + w) * QPW + jq;
        const int b  = q >> 12;
        const int ci = q & (N - 1);
        const float*          Fb  = F  + (size_t)b * N * C;
        const unsigned short* HPb = HP + (size_t)b * N * C;
        const unsigned short* MPb = MP + (size_t)b * N * C;

        const int nb = knn[(size_t)q * K + (l & 15)];

        float4 cA0 = *(const float4*)(Fb + (size_t)ci * C + cb);
        float4 cA1 = *(const float4*)(Fb + (size_t)ci * C + cb + 4);
        float4 cB0 = *(const float4*)(Fb + (size_t)ci * C + 32 + cb);
        float4 cB1 = *(const float4*)(Fb + (size_t)ci * C + 36 + cb);
        float4 nA0 = *(const float4*)(Fb + (size_t)nb * C + cb);
        float4 nA1 = *(const float4*)(Fb + (size_t)nb * C + cb + 4);
        float4 nB0 = *(const float4*)(Fb + (size_t)nb * C + 32 + cb);
        float4 nB1 = *(const float4*)(Fb + (size_t)nb * C + 36 + cb);

        short8 ach0 = *(const short8*)(HPb + (size_t)ci * C + cb);
        short8 ach1 = *(const short8*)(HPb + (size_t)ci * C + 32 + cb);
        short8 acm0 = *(const short8*)(MPb + (size_t)ci * C + cb);
        short8 acm1 = *(const short8*)(MPb + (size_t)ci * C + 32 + cb);

        short8 adh0, adm0, adh1, adm1;
        {
            float d0[8] = {nA0.x - cA0.x, nA0.y - cA0.y, nA0.z - cA0.z, nA0.w - cA0.w,
                           nA1.x - cA1.x, nA1.y - cA1.y, nA1.z - cA1.z, nA1.w - cA1.w};
            float d1[8] = {nB0.x - cB0.x, nB0.y - cB0.y, nB0.z - cB0.z, nB0.w - cB0.w,
                           nB1.x - cB1.x, nB1.y - cB1.y, nB1.z - cB1.z, nB1.w - cB1.w};
            #pragma unroll
            for (int jj = 0; jj < 8; jj++) {
                unsigned short h0 = f2bf(d0[jj]);
                adh0[jj] = (short)h0; adm0[jj] = (short)f2bf(d0[jj] - bf2f(h0));
                unsigned short h1 = f2bf(d1[jj]);
                adh1[jj] = (short)h1; adm1[jj] = (short)f2bf(d1[jj] - bf2f(h1));
            }
        }

        #pragma unroll
        for (int nt = 0; nt < 4; nt++) {
            const int rowb = (nt * 16 + (l & 15)) * 256 + (l >> 4) * 16;
            f32x4 a1 = {0.f, 0.f, 0.f, 0.f};
            f32x4 a2 = {0.f, 0.f, 0.f, 0.f};
            #pragma unroll
            for (int kc = 0; kc < 4; kc++) {
                const int byte = (rowb + kc * 64) ^ swzL;
                short8 Bh = *(const short8*)((char*)W1h + byte);
                short8 Bm = *(const short8*)((char*)W1m + byte);
                short8 Ah = (kc == 0) ? adh0 : (kc == 1) ? adh1 : (kc == 2) ? ach0 : ach1;
                short8 Am = (kc == 0) ? adm0 : (kc == 1) ? adm1 : (kc == 2) ? acm0 : acm1;
                a1 = __builtin_amdgcn_mfma_f32_16x16x32_bf16(Ah, Bh, a1, 0, 0, 0);
                a2 = __builtin_amdgcn_mfma_f32_16x16x32_bf16(Ah, Bm, a2, 0, 0, 0);
                a2 = __builtin_amdgcn_mfma_f32_16x16x32_bf16(Am, Bh, a2, 0, 0, 0);
            }
            #pragma unroll
            for (int r = 0; r < 4; r++) {
                const int row = (l >> 4) * 4 + r;
                const int col = nt * 16 + (l & 15);
                float hv = gelu_exact(a1[r] + a2[r] + b1v[nt]);
                unsigned short hh = f2bf(hv);
                unsigned short hm = f2bf(hv - bf2f(hh));
                const int byte = (row * 128 + col * 2) ^ ((row & 7) << 4);
                *(unsigned short*)((char*)&hbh[w][0] + byte) = hh;
                *(unsigned short*)((char*)&hbm[w][0] + byte) = hm;
            }
        }

        asm volatile("s_waitcnt lgkmcnt(0)" ::: "memory");
        __builtin_amdgcn_sched_barrier(0);

        short8 Ah2[2], Am2[2];
        #pragma unroll
        for (int kc = 0; kc < 2; kc++) {
            const int byte = ((l & 15) * 128 + kc * 64 + (l >> 4) * 16) ^ (((l & 15) & 7) << 4);
            Ah2[kc] = *(const short8*)((char*)&hbh[w][0] + byte);
            Am2[kc] = *(const short8*)((char*)&hbm[w][0] + byte);
        }
        #pragma unroll
        for (int nt = 0; nt < 4; nt++) {
            f32x4 a1 = {0.f, 0.f, 0.f, 0.f};
            f32x4 a2 = {0.f, 0.f, 0.f, 0.f};
            #pragma unroll
            for (int kc = 0; kc < 2; kc++) {
                a1 = __builtin_amdgcn_mfma_f32_16x16x32_bf16(Ah2[kc], B2h[nt][kc], a1, 0, 0, 0);
                a2 = __builtin_amdgcn_mfma_f32_16x16x32_bf16(Ah2[kc], B2m[nt][kc], a2, 0, 0, 0);
                a2 = __builtin_amdgcn_mfma_f32_16x16x32_bf16(Am2[kc], B2h[nt][kc], a2, 0, 0, 0);
            }
            float mx = -INFINITY;
            #pragma unroll
            for (int r = 0; r < 4; r++)
                mx = fmaxf(mx, gelu_exact(a1[r] + a2[r] + b2v[nt]));
            mx = fmaxf(mx, __shfl_xor(mx, 16));
            mx = fmaxf(mx, __shfl_xor(mx, 32));
            if (l < 16) out[(size_t)q * D + nt * 16 + l] = mx;
        }
    }
}

// ---------------------------------------------------------------------------
extern "C" void kernel_launch(void* const* d_in, const int* in_sizes, int n_in,
                              void* d_out, int out_size, void* d_ws, size_t ws_size,
                              hipStream_t stream) {
    const float* F  = (const float*)d_in[0];
    const float* W1 = (const float*)d_in[1];
    const float* b1 = (const float*)d_in[2];
    const float* W2 = (const float*)d_in[3];
    const float* b2 = (const float*)d_in[4];
    float* out = (float*)d_out;

    char* ws = (char*)d_ws;
    float*          sq   = (float*)ws;                             // 128 KB
    uint64_t*       keys = (uint64_t*)(ws + (128 << 10));          // 8 MB
    unsigned short* HP   = (unsigned short*)(ws + (8320 << 10));   // 4 MB
    unsigned short* MP   = (unsigned short*)(ws + (12416 << 10));  // 4 MB
    unsigned short* LP   = (unsigned short*)(ws + (16512 << 10));  // 4 MB
    int*            knn  = (int*)LP;   // LP dead after knn_mfma pass (mlp uses HP/MP only)

    prep_kernel<<<dim3(B * N / 256), 256, 0, stream>>>(F, sq, HP, MP, LP);
    knn_mfma_kernel<<<dim3(N / 64, 2, B), 256, 0, stream>>>(HP, MP, LP, sq, keys);
    knn_merge_kernel<<<dim3(B * N / 256), 256, 0, stream>>>(keys, knn);
    mlp_mfma_kernel<<<dim3(B * N / (4 * QPW)), 256, 0, stream>>>(
        F, HP, MP, knn, W1, b1, W2, b2, out);
}

// Round 10
// 291.748 us; speedup vs baseline: 2.6838x; 1.0350x over previous
//
#include <hip/hip_runtime.h>
#include <math.h>
#include <stdint.h>

#define B 8
#define N 4096
#define C 64
#define D 64
#define K 16

typedef __attribute__((ext_vector_type(8))) short short8;
typedef __attribute__((ext_vector_type(4))) float f32x4;

// ---------------------------------------------------------------------------
// bf16 helpers
// ---------------------------------------------------------------------------
__device__ __forceinline__ unsigned short f2bf(float x) {
    unsigned u = __float_as_uint(x);
    unsigned r = (u + 0x7FFFu + ((u >> 16) & 1u)) >> 16;   // RNE
    return (unsigned short)r;
}
__device__ __forceinline__ float bf2f(unsigned short h) {
    return __uint_as_float(((unsigned)h) << 16);
}

// key = (d2bits<<32)|idx reinterpreted as double. d2 finite >=0 -> positive
// finite double -> IEEE ordering == integer ordering (exact tie-break kept).
__device__ __forceinline__ double pack_key(float d2, unsigned idx) {
    uint2 u; u.x = idx; u.y = __float_as_uint(d2);
    return __builtin_bit_cast(double, u);
}

// ---------------------------------------------------------------------------
// Kernel 0: per-row sqnorm (round-1 arithmetic, passed) + 3-term bf16 split
// ---------------------------------------------------------------------------
__global__ __launch_bounds__(256)
void prep_kernel(const float* __restrict__ F, float* __restrict__ sq,
                 unsigned short* __restrict__ HP, unsigned short* __restrict__ MP,
                 unsigned short* __restrict__ LP) {
    const int row = blockIdx.x * 256 + threadIdx.x;
    const float4* src = (const float4*)(F + (size_t)row * C);
    float4 v[16];
    #pragma unroll
    for (int q = 0; q < 16; q++) v[q] = src[q];

    {
        float r[8];
        #pragma unroll
        for (int j = 0; j < 8; j++) {
            float t = ((const float*)v)[j];
            r[j] = t * t;
        }
        #pragma unroll
        for (int m = 1; m < 8; m++) {
            #pragma unroll
            for (int j = 0; j < 8; j++) {
                float t = ((const float*)v)[8 * m + j];
                r[j] = fmaf(t, t, r[j]);
            }
        }
        sq[row] = ((r[0] + r[1]) + (r[2] + r[3])) + ((r[4] + r[5]) + (r[6] + r[7]));
    }

    uint4* dh = (uint4*)(HP + (size_t)row * C);
    uint4* dm = (uint4*)(MP + (size_t)row * C);
    uint4* dl = (uint4*)(LP + (size_t)row * C);
    #pragma unroll
    for (int c8 = 0; c8 < 8; c8++) {
        unsigned hq[4], mq[4], lq[4];
        #pragma unroll
        for (int e = 0; e < 4; e++) {
            float x0 = ((const float*)v)[c8 * 8 + 2 * e];
            float x1 = ((const float*)v)[c8 * 8 + 2 * e + 1];
            unsigned short h0 = f2bf(x0), h1 = f2bf(x1);
            float r10 = x0 - bf2f(h0), r11 = x1 - bf2f(h1);
            unsigned short m0 = f2bf(r10), m1 = f2bf(r11);
            float r20 = r10 - bf2f(m0), r21 = r11 - bf2f(m1);
            unsigned short l0 = f2bf(r20), l1 = f2bf(r21);
            hq[e] = (unsigned)h0 | ((unsigned)h1 << 16);
            mq[e] = (unsigned)m0 | ((unsigned)m1 << 16);
            lq[e] = (unsigned)l0 | ((unsigned)l1 << 16);
        }
        dh[c8] = make_uint4(hq[0], hq[1], hq[2], hq[3]);
        dm[c8] = make_uint4(mq[0], mq[1], mq[2], mq[3]);
        dl[c8] = make_uint4(lq[0], lq[1], lq[2], lq[3]);
    }
}

// ---------------------------------------------------------------------------
// 4-way merge of sorted lists for one query -> 16 sorted keys to dst
// ---------------------------------------------------------------------------
__device__ __forceinline__ void merge4_store(const uint64_t* __restrict__ keys,
                                             int qloc, uint64_t* __restrict__ dst) {
    const uint64_t* K0 = keys + (qloc * 4 + 0) * 16;
    const uint64_t* K1 = keys + (qloc * 4 + 1) * 16;
    const uint64_t* K2 = keys + (qloc * 4 + 2) * 16;
    const uint64_t* K3 = keys + (qloc * 4 + 3) * 16;
    int p0 = 0, p1 = 0, p2 = 0, p3 = 0;
    uint64_t h0 = K0[0], h1 = K1[0], h2 = K2[0], h3 = K3[0];
    #pragma unroll
    for (int k = 0; k < K; k++) {
        uint64_t m01 = h0 < h1 ? h0 : h1;
        uint64_t m23 = h2 < h3 ? h2 : h3;
        uint64_t mv  = m01 < m23 ? m01 : m23;
        dst[k] = mv;
        if      (mv == h0) { ++p0; h0 = (p0 < 16) ? K0[p0] : ~0ull; }
        else if (mv == h1) { ++p1; h1 = (p1 < 16) ? K1[p1] : ~0ull; }
        else if (mv == h2) { ++p2; h2 = (p2 < 16) ? K2[p2] : ~0ull; }
        else               { ++p3; h3 = (p3 < 16) ? K3[p3] : ~0ull; }
    }
}

// ---------------------------------------------------------------------------
// Kernel 1: MFMA KNN. Block = 512 threads / 8 waves sharing one candidate
// pipeline; 128 queries/block (wave w owns queries w*16..w*16+15), split-K x2.
// Engine (MFMA chains, f64 bitonic selection, dbuf) identical to round 9.
// ---------------------------------------------------------------------------
__global__ __launch_bounds__(512, 2)
void knn_mfma_kernel(const unsigned short* __restrict__ HP,
                     const unsigned short* __restrict__ MP,
                     const unsigned short* __restrict__ LP,
                     const float* __restrict__ sqg, uint64_t* __restrict__ keysg) {
    __shared__ __align__(16) char lds[49152];   // buf0 = [0,24K), buf1 = [24K,48K)

    const int s  = blockIdx.y;                  // candidate half
    const int b  = blockIdx.z;
    const int i0 = blockIdx.x * 128;            // first query of block
    const int c0 = s * 2048;
    const unsigned short* Hb = HP + (size_t)b * N * C;
    const unsigned short* Mb = MP + (size_t)b * N * C;
    const unsigned short* Lb = LP + (size_t)b * N * C;
    const float* sqb = sqg + (size_t)b * N;

    const int tid = threadIdx.x;
    const int l   = tid & 63;
    const int w   = tid >> 6;                   // 0..7

    // staging geometry: 512 threads cover 64 rows x 128B per plane (1 uint4 ea)
    const int lr  = tid >> 3;                   // row 0..63
    const int lq  = tid & 7;                    // 16B chunk 0..7
    const int wbyte = (lr * 128 + lq * 16) ^ ((lr & 7) << 4);

    const double KMAX = __builtin_bit_cast(double, 0x7FEFFFFFFFFFFFFFull);

    // prefetch first candidate tile of this half (hides under Q staging)
    uint4 ph, pm, pl;
    {
        const size_t rb = (size_t)(c0 + lr) * C + lq * 8;
        ph = *(const uint4*)(Hb + rb);
        pm = *(const uint4*)(Mb + rb);
        pl = *(const uint4*)(Lb + rb);
    }

    {   // stage ALL 128 Q rows across both buffers (48KB)
        const size_t r0 = (size_t)(i0 + lr) * C + lq * 8;
        const size_t r1 = (size_t)(i0 + 64 + lr) * C + lq * 8;
        uint4 qh0 = *(const uint4*)(Hb + r0), qh1 = *(const uint4*)(Hb + r1);
        uint4 qm0 = *(const uint4*)(Mb + r0), qm1 = *(const uint4*)(Mb + r1);
        uint4 ql0 = *(const uint4*)(Lb + r0), ql1 = *(const uint4*)(Lb + r1);
        *(uint4*)(lds +              wbyte) = qh0;
        *(uint4*)(lds +  8192      + wbyte) = qm0;
        *(uint4*)(lds + 16384      + wbyte) = ql0;
        *(uint4*)(lds + 24576      + wbyte) = qh1;
        *(uint4*)(lds + 24576+8192 + wbyte) = qm1;
        *(uint4*)(lds + 24576+16384+ wbyte) = ql1;
    }
    __syncthreads();

    // B fragments (query), register-resident for the whole scan
    const int koff = (l >> 4) * 16;
    const int swzR = (l & 7) << 4;
    const int qrow = w * 16 + (l & 15);         // 0..127
    const char* qbuf = lds + ((qrow >> 6) ? 24576 : 0);
    const int qr6 = qrow & 63;
    const int qb0 = (qr6 * 128 + koff) ^ swzR;
    const int qb1 = (qr6 * 128 + 64 + koff) ^ swzR;
    short8 bh0 = *(const short8*)(qbuf + qb0),         bh1 = *(const short8*)(qbuf + qb1);
    short8 bm0 = *(const short8*)(qbuf +  8192 + qb0), bm1 = *(const short8*)(qbuf +  8192 + qb1);
    short8 bl0 = *(const short8*)(qbuf + 16384 + qb0), bl1 = *(const short8*)(qbuf + 16384 + qb1);

    const float sqq   = sqb[i0 + qrow];
    const int   qglob = i0 + qrow;
    const int   crow0 = (l >> 4) * 4;
    const int   dtile = i0 + ((w >> 2) << 6);   // wave-uniform diagonal tile

    __syncthreads();          // all waves finished reading Q

    // stage first candidate tile into buf0
    *(uint4*)(lds +         wbyte) = ph;
    *(uint4*)(lds +  8192 + wbyte) = pm;
    *(uint4*)(lds + 16384 + wbyte) = pl;
    {   // prefetch second tile
        const size_t rb = (size_t)(c0 + 64 + lr) * C + lq * 8;
        ph = *(const uint4*)(Hb + rb);
        pm = *(const uint4*)(Mb + rb);
        pl = *(const uint4*)(Lb + rb);
    }
    __syncthreads();          // first tile visible

    double bd[16];
    #pragma unroll
    for (int k = 0; k < 16; k++) bd[k] = KMAX;

    for (int t = 0; t < 32; t++) {
        const int j0 = c0 + t * 64;
        char* bufA = lds + ((t & 1) ? 24576 : 0);      // compute tile t
        char* bufB = lds + ((t & 1) ? 0 : 24576);      // stage tile t+1

        if (t < 31) {
            *(uint4*)(bufB +         wbyte) = ph;
            *(uint4*)(bufB +  8192 + wbyte) = pm;
            *(uint4*)(bufB + 16384 + wbyte) = pl;
        }
        if (t < 30) {
            const size_t rb = (size_t)(j0 + 128 + lr) * C + lq * 8;
            ph = *(const uint4*)(Hb + rb);
            pm = *(const uint4*)(Mb + rb);
            pl = *(const uint4*)(Lb + rb);
        }

        float4 sqm0 = *(const float4*)(sqb + j0 +      crow0);
        float4 sqm1 = *(const float4*)(sqb + j0 + 16 + crow0);
        float4 sqm2 = *(const float4*)(sqb + j0 + 32 + crow0);
        float4 sqm3 = *(const float4*)(sqb + j0 + 48 + crow0);

        double nk[16];

        #pragma unroll
        for (int m = 0; m < 4; m++) {
            const int arow = m * 16 + (l & 15);
            const int ab0 = (arow * 128 + koff) ^ swzR;
            const int ab1 = (arow * 128 + 64 + koff) ^ swzR;
            short8 ah0 = *(const short8*)(bufA + ab0);
            short8 ah1 = *(const short8*)(bufA + ab1);
            short8 am0 = *(const short8*)(bufA + 8192 + ab0);
            short8 am1 = *(const short8*)(bufA + 8192 + ab1);
            short8 al0 = *(const short8*)(bufA + 16384 + ab0);
            short8 al1 = *(const short8*)(bufA + 16384 + ab1);

            f32x4 acc1 = {0.f, 0.f, 0.f, 0.f};
            acc1 = __builtin_amdgcn_mfma_f32_16x16x32_bf16(am0, bm0, acc1, 0, 0, 0);
            acc1 = __builtin_amdgcn_mfma_f32_16x16x32_bf16(am1, bm1, acc1, 0, 0, 0);
            acc1 = __builtin_amdgcn_mfma_f32_16x16x32_bf16(ah0, bl0, acc1, 0, 0, 0);
            acc1 = __builtin_amdgcn_mfma_f32_16x16x32_bf16(ah1, bl1, acc1, 0, 0, 0);
            acc1 = __builtin_amdgcn_mfma_f32_16x16x32_bf16(al0, bh0, acc1, 0, 0, 0);
            f32x4 acc2 = {0.f, 0.f, 0.f, 0.f};
            acc2 = __builtin_amdgcn_mfma_f32_16x16x32_bf16(al1, bh1, acc2, 0, 0, 0);
            acc2 = __builtin_amdgcn_mfma_f32_16x16x32_bf16(ah0, bm0, acc2, 0, 0, 0);
            acc2 = __builtin_amdgcn_mfma_f32_16x16x32_bf16(ah1, bm1, acc2, 0, 0, 0);
            acc2 = __builtin_amdgcn_mfma_f32_16x16x32_bf16(am0, bh0, acc2, 0, 0, 0);
            acc2 = __builtin_amdgcn_mfma_f32_16x16x32_bf16(am1, bh1, acc2, 0, 0, 0);
            f32x4 acch = {0.f, 0.f, 0.f, 0.f};
            acch = __builtin_amdgcn_mfma_f32_16x16x32_bf16(ah0, bh0, acch, 0, 0, 0);
            acch = __builtin_amdgcn_mfma_f32_16x16x32_bf16(ah1, bh1, acch, 0, 0, 0);

            float4 sqm = (m == 0) ? sqm0 : (m == 1) ? sqm1 : (m == 2) ? sqm2 : sqm3;
            #pragma unroll
            for (int r = 0; r < 4; r++) {
                float sqc = (r == 0) ? sqm.x : (r == 1) ? sqm.y : (r == 2) ? sqm.z : sqm.w;
                float gg = acch[r] + (acc1[r] + acc2[r]);
                float d2 = fmaf(-2.0f, gg, sqq + sqc);
                d2 = fmaxf(d2, 0.0f);
                nk[m * 4 + r] = pack_key(d2, (unsigned)(j0 + m * 16 + crow0 + r));
            }
        }

        // diagonal tile only: kill self-match (wave-uniform branch)
        if (j0 == dtile) {
            #pragma unroll
            for (int m = 0; m < 4; m++)
                #pragma unroll
                for (int r = 0; r < 4; r++)
                    if ((j0 + m * 16 + crow0 + r) == qglob) nk[m * 4 + r] = KMAX;
        }

        // ---- bitonic sort nk DESCENDING via fmin/fmax (2-instr CAS) ----
        #pragma unroll
        for (int kk = 2; kk <= 16; kk <<= 1) {
            #pragma unroll
            for (int j = kk >> 1; j > 0; j >>= 1) {
                #pragma unroll
                for (int i = 0; i < 16; i++) {
                    int ixj = i ^ j;
                    if (ixj > i) {
                        bool asc = ((i & kk) != 0);
                        double a = nk[i], c = nk[ixj];
                        nk[i]   = asc ? fmin(a, c) : fmax(a, c);
                        nk[ixj] = asc ? fmax(a, c) : fmin(a, c);
                    }
                }
            }
        }
        #pragma unroll
        for (int i = 0; i < 16; i++) bd[i] = fmin(bd[i], nk[i]);
        #pragma unroll
        for (int j = 8; j > 0; j >>= 1) {
            #pragma unroll
            for (int i = 0; i < 16; i++) {
                int ixj = i ^ j;
                if (ixj > i) {
                    double a = bd[i], c = bd[ixj];
                    bd[i]   = fmin(a, c);
                    bd[ixj] = fmax(a, c);
                }
            }
        }

        __syncthreads();       // tile t+1 staged & prior reads done
    }

    // ---- epilogue: two 64-query passes (32KB key scratch each) ----
    uint64_t* keys = (uint64_t*)lds;
    if (w < 4) {               // pass A: queries i0..i0+63
        const int qloc = w * 16 + (l & 15);
        const int base = (qloc * 4 + (l >> 4)) * 16;
        #pragma unroll
        for (int k = 0; k < 16; k++)
            keys[base + k] = __builtin_bit_cast(uint64_t, bd[k]);
    }
    __syncthreads();
    if (tid < 64)
        merge4_store(keys, tid, keysg + ((size_t)b * N + i0 + tid) * 32 + s * 16);
    __syncthreads();
    if (w >= 4) {              // pass B: queries i0+64..i0+127
        const int qloc = (w - 4) * 16 + (l & 15);
        const int base = (qloc * 4 + (l >> 4)) * 16;
        #pragma unroll
        for (int k = 0; k < 16; k++)
            keys[base + k] = __builtin_bit_cast(uint64_t, bd[k]);
    }
    __syncthreads();
    if (tid < 64)
        merge4_store(keys, tid, keysg + ((size_t)b * N + i0 + 64 + tid) * 32 + s * 16);
}

// ---------------------------------------------------------------------------
// Kernel 1b: final 2-way merge of the two halves, one thread per query
// ---------------------------------------------------------------------------
__global__ __launch_bounds__(256)
void knn_merge_kernel(const uint64_t* __restrict__ keysg, int* __restrict__ knn) {
    const int q = blockIdx.x * 256 + threadIdx.x;     // 0..B*N-1
    const uint64_t* A  = keysg + (size_t)q * 32;
    const uint64_t* Bp = A + 16;
    int pa = 0, pb = 0;
    uint64_t ha = A[0], hb = Bp[0];
    int* dst = knn + (size_t)q * K;
    #pragma unroll
    for (int k = 0; k < K; k++) {
        uint64_t mv = ha < hb ? ha : hb;
        dst[k] = (int)(mv & 0xFFFFFFFFu);
        if (mv == ha) { ++pa; ha = (pa < 16) ? A[pa] : ~0ull; }
        else          { ++pb; hb = (pb < 16) ? Bp[pb] : ~0ull; }
    }
}

// ---------------------------------------------------------------------------
// Kernel 2: MFMA MLP (round-8, unchanged — passed at ~80us)
// ---------------------------------------------------------------------------
__device__ __forceinline__ float gelu_exact(float x) {
    return 0.5f * x * (1.0f + erff(x * 0.70710678118654752440f));
}

#define QPW 4

__global__ __launch_bounds__(256)
void mlp_mfma_kernel(const float* __restrict__ F,
                     const unsigned short* __restrict__ HP,
                     const unsigned short* __restrict__ MP,
                     const int* __restrict__ knn,
                     const float* __restrict__ W1, const float* __restrict__ b1,
                     const float* __restrict__ W2, const float* __restrict__ b2,
                     float* __restrict__ out) {
    __shared__ __align__(16) unsigned short W1h[64 * 128];   // 16KB
    __shared__ __align__(16) unsigned short W1m[64 * 128];   // 16KB
    __shared__ __align__(16) unsigned short hbh[4][1024];
    __shared__ __align__(16) unsigned short hbm[4][1024];

    const int tid = threadIdx.x;
    const int l   = tid & 63;
    const int w   = tid >> 6;

    for (int e = tid; e < 8192; e += 256) {
        const int n = e & 63, k = e >> 6;
        const int srcrow = (k < 64) ? (64 + k) : (k - 64);
        float x = W1[srcrow * 64 + n];
        unsigned short hh = f2bf(x);
        unsigned short mm = f2bf(x - bf2f(hh));
        const int byte = (n * 256 + k * 2) ^ ((n & 15) << 4);
        *(unsigned short*)((char*)W1h + byte) = hh;
        *(unsigned short*)((char*)W1m + byte) = mm;
    }

    short8 B2h[4][2], B2m[4][2];
    float b1v[4], b2v[4];
    {
        const int n = (l & 15);
        #pragma unroll
        for (int nt = 0; nt < 4; nt++) {
            const int nn = nt * 16 + n;
            b1v[nt] = b1[nn];
            b2v[nt] = b2[nn];
            #pragma unroll
            for (int c = 0; c < 2; c++) {
                const int k0 = c * 32 + (l >> 4) * 8;
                short8 vh, vm;
                #pragma unroll
                for (int jj = 0; jj < 8; jj++) {
                    float x = W2[(k0 + jj) * 64 + nn];
                    unsigned short hh = f2bf(x);
                    vh[jj] = (short)hh;
                    vm[jj] = (short)f2bf(x - bf2f(hh));
                }
                B2h[nt][c] = vh; B2m[nt][c] = vm;
            }
        }
    }
    __syncthreads();

    const int cb   = (l >> 4) * 8;
    const int swzL = (l & 15) << 4;

    for (int jq = 0; jq < QPW; jq++) {
        const int q  = (blockIdx.x * 4 + w) * QPW + jq;
        const int b  = q >> 12;
        const int ci = q & (N - 1);
        const float*          Fb  = F  + (size_t)b * N * C;
        const unsigned short* HPb = HP + (size_t)b * N * C;
        const unsigned short* MPb = MP + (size_t)b * N * C;

        const int nb = knn[(size_t)q * K + (l & 15)];

        float4 cA0 = *(const float4*)(Fb + (size_t)ci * C + cb);
        float4 cA1 = *(const float4*)(Fb + (size_t)ci * C + cb + 4);
        float4 cB0 = *(const float4*)(Fb + (size_t)ci * C + 32 + cb);
        float4 cB1 = *(const float4*)(Fb + (size_t)ci * C + 36 + cb);
        float4 nA0 = *(const float4*)(Fb + (size_t)nb * C + cb);
        float4 nA1 = *(const float4*)(Fb + (size_t)nb * C + cb + 4);
        float4 nB0 = *(const float4*)(Fb + (size_t)nb * C + 32 + cb);
        float4 nB1 = *(const float4*)(Fb + (size_t)nb * C + 36 + cb);

        short8 ach0 = *(const short8*)(HPb + (size_t)ci * C + cb);
        short8 ach1 = *(const short8*)(HPb + (size_t)ci * C + 32 + cb);
        short8 acm0 = *(const short8*)(MPb + (size_t)ci * C + cb);
        short8 acm1 = *(const short8*)(MPb + (size_t)ci * C + 32 + cb);

        short8 adh0, adm0, adh1, adm1;
        {
            float d0[8] = {nA0.x - cA0.x, nA0.y - cA0.y, nA0.z - cA0.z, nA0.w - cA0.w,
                           nA1.x - cA1.x, nA1.y - cA1.y, nA1.z - cA1.z, nA1.w - cA1.w};
            float d1[8] = {nB0.x - cB0.x, nB0.y - cB0.y, nB0.z - cB0.z, nB0.w - cB0.w,
                           nB1.x - cB1.x, nB1.y - cB1.y, nB1.z - cB1.z, nB1.w - cB1.w};
            #pragma unroll
            for (int jj = 0; jj < 8; jj++) {
                unsigned short h0 = f2bf(d0[jj]);
                adh0[jj] = (short)h0; adm0[jj] = (short)f2bf(d0[jj] - bf2f(h0));
                unsigned short h1 = f2bf(d1[jj]);
                adh1[jj] = (short)h1; adm1[jj] = (short)f2bf(d1[jj] - bf2f(h1));
            }
        }

        #pragma unroll
        for (int nt = 0; nt < 4; nt++) {
            const int rowb = (nt * 16 + (l & 15)) * 256 + (l >> 4) * 16;
            f32x4 a1 = {0.f, 0.f, 0.f, 0.f};
            f32x4 a2 = {0.f, 0.f, 0.f, 0.f};
            #pragma unroll
            for (int kc = 0; kc < 4; kc++) {
                const int byte = (rowb + kc * 64) ^ swzL;
                short8 Bh = *(const short8*)((char*)W1h + byte);
                short8 Bm = *(const short8*)((char*)W1m + byte);
                short8 Ah = (kc == 0) ? adh0 : (kc == 1) ? adh1 : (kc == 2) ? ach0 : ach1;
                short8 Am = (kc == 0) ? adm0 : (kc == 1) ? adm1 : (kc == 2) ? acm0 : acm1;
                a1 = __builtin_amdgcn_mfma_f32_16x16x32_bf16(Ah, Bh, a1, 0, 0, 0);
                a2 = __builtin_amdgcn_mfma_f32_16x16x32_bf16(Ah, Bm, a2, 0, 0, 0);
                a2 = __builtin_amdgcn_mfma_f32_16x16x32_bf16(Am, Bh, a2, 0, 0, 0);
            }
            #pragma unroll
            for (int r = 0; r < 4; r++) {
                const int row = (l >> 4) * 4 + r;
                const int col = nt * 16 + (l & 15);
                float hv = gelu_exact(a1[r] + a2[r] + b1v[nt]);
                unsigned short hh = f2bf(hv);
                unsigned short hm = f2bf(hv - bf2f(hh));
                const int byte = (row * 128 + col * 2) ^ ((row & 7) << 4);
                *(unsigned short*)((char*)&hbh[w][0] + byte) = hh;
                *(unsigned short*)((char*)&hbm[w][0] + byte) = hm;
            }
        }

        asm volatile("s_waitcnt lgkmcnt(0)" ::: "memory");
        __builtin_amdgcn_sched_barrier(0);

        short8 Ah2[2], Am2[2];
        #pragma unroll
        for (int kc = 0; kc < 2; kc++) {
            const int byte = ((l & 15) * 128 + kc * 64 + (l >> 4) * 16) ^ (((l & 15) & 7) << 4);
            Ah2[kc] = *(const short8*)((char*)&hbh[w][0] + byte);
            Am2[kc] = *(const short8*)((char*)&hbm[w][0] + byte);
        }
        #pragma unroll
        for (int nt = 0; nt < 4; nt++) {
            f32x4 a1 = {0.f, 0.f, 0.f, 0.f};
            f32x4 a2 = {0.f, 0.f, 0.f, 0.f};
            #pragma unroll
            for (int kc = 0; kc < 2; kc++) {
                a1 = __builtin_amdgcn_mfma_f32_16x16x32_bf16(Ah2[kc], B2h[nt][kc], a1, 0, 0, 0);
                a2 = __builtin_amdgcn_mfma_f32_16x16x32_bf16(Ah2[kc], B2m[nt][kc], a2, 0, 0, 0);
                a2 = __builtin_amdgcn_mfma_f32_16x16x32_bf16(Am2[kc], B2h[nt][kc], a2, 0, 0, 0);
            }
            float mx = -INFINITY;
            #pragma unroll
            for (int r = 0; r < 4; r++)
                mx = fmaxf(mx, gelu_exact(a1[r] + a2[r] + b2v[nt]));
            mx = fmaxf(mx, __shfl_xor(mx, 16));
            mx = fmaxf(mx, __shfl_xor(mx, 32));
            if (l < 16) out[(size_t)q * D + nt * 16 + l] = mx;
        }
    }
}

// ---------------------------------------------------------------------------
extern "C" void kernel_launch(void* const* d_in, const int* in_sizes, int n_in,
                              void* d_out, int out_size, void* d_ws, size_t ws_size,
                              hipStream_t stream) {
    const float* F  = (const float*)d_in[0];
    const float* W1 = (const float*)d_in[1];
    const float* b1 = (const float*)d_in[2];
    const float* W2 = (const float*)d_in[3];
    const float* b2 = (const float*)d_in[4];
    float* out = (float*)d_out;

    char* ws = (char*)d_ws;
    float*          sq   = (float*)ws;                             // 128 KB
    uint64_t*       keys = (uint64_t*)(ws + (128 << 10));          // 8 MB
    unsigned short* HP   = (unsigned short*)(ws + (8320 << 10));   // 4 MB
    unsigned short* MP   = (unsigned short*)(ws + (12416 << 10));  // 4 MB
    unsigned short* LP   = (unsigned short*)(ws + (16512 << 10));  // 4 MB
    int*            knn  = (int*)LP;   // LP dead after knn_mfma pass (mlp uses HP/MP only)

    prep_kernel<<<dim3(B * N / 256), 256, 0, stream>>>(F, sq, HP, MP, LP);
    knn_mfma_kernel<<<dim3(N / 128, 2, B), 512, 0, stream>>>(HP, MP, LP, sq, keys);
    knn_merge_kernel<<<dim3(B * N / 256), 256, 0, stream>>>(keys, knn);
    mlp_mfma_kernel<<<dim3(B * N / (4 * QPW)), 256, 0, stream>>>(
        F, HP, MP, knn, W1, b1, W2, b2, out);
}

// Round 11
// 276.569 us; speedup vs baseline: 2.8310x; 1.0549x over previous
//
#include <hip/hip_runtime.h>
#include <math.h>
#include <stdint.h>

#define B 8
#define N 4096
#define C 64
#define D 64
#define K 16

typedef __attribute__((ext_vector_type(8))) short short8;
typedef __attribute__((ext_vector_type(4))) float f32x4;

// ---------------------------------------------------------------------------
// bf16 helpers
// ---------------------------------------------------------------------------
__device__ __forceinline__ unsigned short f2bf(float x) {
    unsigned u = __float_as_uint(x);
    unsigned r = (u + 0x7FFFu + ((u >> 16) & 1u)) >> 16;   // RNE
    return (unsigned short)r;
}
__device__ __forceinline__ float bf2f(unsigned short h) {
    return __uint_as_float(((unsigned)h) << 16);
}

// key = (d2bits<<32)|idx reinterpreted as double. d2 finite >=0 -> positive
// finite double -> IEEE ordering == integer ordering (exact tie-break kept).
__device__ __forceinline__ double pack_key(float d2, unsigned idx) {
    uint2 u; u.x = idx; u.y = __float_as_uint(d2);
    return __builtin_bit_cast(double, u);
}

// ---------------------------------------------------------------------------
// Kernel 0: per-row sqnorm (round-1 arithmetic, passed) + 3-term bf16 split
// ---------------------------------------------------------------------------
__global__ __launch_bounds__(256)
void prep_kernel(const float* __restrict__ F, float* __restrict__ sq,
                 unsigned short* __restrict__ HP, unsigned short* __restrict__ MP,
                 unsigned short* __restrict__ LP) {
    const int row = blockIdx.x * 256 + threadIdx.x;
    const float4* src = (const float4*)(F + (size_t)row * C);
    float4 v[16];
    #pragma unroll
    for (int q = 0; q < 16; q++) v[q] = src[q];

    {
        float r[8];
        #pragma unroll
        for (int j = 0; j < 8; j++) {
            float t = ((const float*)v)[j];
            r[j] = t * t;
        }
        #pragma unroll
        for (int m = 1; m < 8; m++) {
            #pragma unroll
            for (int j = 0; j < 8; j++) {
                float t = ((const float*)v)[8 * m + j];
                r[j] = fmaf(t, t, r[j]);
            }
        }
        sq[row] = ((r[0] + r[1]) + (r[2] + r[3])) + ((r[4] + r[5]) + (r[6] + r[7]));
    }

    uint4* dh = (uint4*)(HP + (size_t)row * C);
    uint4* dm = (uint4*)(MP + (size_t)row * C);
    uint4* dl = (uint4*)(LP + (size_t)row * C);
    #pragma unroll
    for (int c8 = 0; c8 < 8; c8++) {
        unsigned hq[4], mq[4], lq[4];
        #pragma unroll
        for (int e = 0; e < 4; e++) {
            float x0 = ((const float*)v)[c8 * 8 + 2 * e];
            float x1 = ((const float*)v)[c8 * 8 + 2 * e + 1];
            unsigned short h0 = f2bf(x0), h1 = f2bf(x1);
            float r10 = x0 - bf2f(h0), r11 = x1 - bf2f(h1);
            unsigned short m0 = f2bf(r10), m1 = f2bf(r11);
            float r20 = r10 - bf2f(m0), r21 = r11 - bf2f(m1);
            unsigned short l0 = f2bf(r20), l1 = f2bf(r21);
            hq[e] = (unsigned)h0 | ((unsigned)h1 << 16);
            mq[e] = (unsigned)m0 | ((unsigned)m1 << 16);
            lq[e] = (unsigned)l0 | ((unsigned)l1 << 16);
        }
        dh[c8] = make_uint4(hq[0], hq[1], hq[2], hq[3]);
        dm[c8] = make_uint4(mq[0], mq[1], mq[2], mq[3]);
        dl[c8] = make_uint4(lq[0], lq[1], lq[2], lq[3]);
    }
}

// ---------------------------------------------------------------------------
// 4-way merge of sorted lists for one query -> 16 sorted keys to dst
// ---------------------------------------------------------------------------
__device__ __forceinline__ void merge4_store(const uint64_t* __restrict__ keys,
                                             int qloc, uint64_t* __restrict__ dst) {
    const uint64_t* K0 = keys + (qloc * 4 + 0) * 16;
    const uint64_t* K1 = keys + (qloc * 4 + 1) * 16;
    const uint64_t* K2 = keys + (qloc * 4 + 2) * 16;
    const uint64_t* K3 = keys + (qloc * 4 + 3) * 16;
    int p0 = 0, p1 = 0, p2 = 0, p3 = 0;
    uint64_t h0 = K0[0], h1 = K1[0], h2 = K2[0], h3 = K3[0];
    #pragma unroll
    for (int k = 0; k < K; k++) {
        uint64_t m01 = h0 < h1 ? h0 : h1;
        uint64_t m23 = h2 < h3 ? h2 : h3;
        uint64_t mv  = m01 < m23 ? m01 : m23;
        dst[k] = mv;
        if      (mv == h0) { ++p0; h0 = (p0 < 16) ? K0[p0] : ~0ull; }
        else if (mv == h1) { ++p1; h1 = (p1 < 16) ? K1[p1] : ~0ull; }
        else if (mv == h2) { ++p2; h2 = (p2 < 16) ? K2[p2] : ~0ull; }
        else               { ++p3; h3 = (p3 < 16) ? K3[p3] : ~0ull; }
    }
}

// ---------------------------------------------------------------------------
// Kernel 1: MFMA KNN. Block = 512 threads / 8 waves sharing one candidate
// pipeline; 128 queries/block, split-K x2. Engine identical to round 10
// except the per-tile sort: Batcher odd-even mergesort (63 comparators,
// DESCENDING) instead of bitonic (80).
// ---------------------------------------------------------------------------
__global__ __launch_bounds__(512, 2)
void knn_mfma_kernel(const unsigned short* __restrict__ HP,
                     const unsigned short* __restrict__ MP,
                     const unsigned short* __restrict__ LP,
                     const float* __restrict__ sqg, uint64_t* __restrict__ keysg) {
    __shared__ __align__(16) char lds[49152];   // buf0 = [0,24K), buf1 = [24K,48K)

    const int s  = blockIdx.y;                  // candidate half
    const int b  = blockIdx.z;
    const int i0 = blockIdx.x * 128;            // first query of block
    const int c0 = s * 2048;
    const unsigned short* Hb = HP + (size_t)b * N * C;
    const unsigned short* Mb = MP + (size_t)b * N * C;
    const unsigned short* Lb = LP + (size_t)b * N * C;
    const float* sqb = sqg + (size_t)b * N;

    const int tid = threadIdx.x;
    const int l   = tid & 63;
    const int w   = tid >> 6;                   // 0..7

    const int lr  = tid >> 3;                   // row 0..63
    const int lq  = tid & 7;                    // 16B chunk 0..7
    const int wbyte = (lr * 128 + lq * 16) ^ ((lr & 7) << 4);

    const double KMAX = __builtin_bit_cast(double, 0x7FEFFFFFFFFFFFFFull);

    // prefetch first candidate tile of this half (hides under Q staging)
    uint4 ph, pm, pl;
    {
        const size_t rb = (size_t)(c0 + lr) * C + lq * 8;
        ph = *(const uint4*)(Hb + rb);
        pm = *(const uint4*)(Mb + rb);
        pl = *(const uint4*)(Lb + rb);
    }

    {   // stage ALL 128 Q rows across both buffers (48KB)
        const size_t r0 = (size_t)(i0 + lr) * C + lq * 8;
        const size_t r1 = (size_t)(i0 + 64 + lr) * C + lq * 8;
        uint4 qh0 = *(const uint4*)(Hb + r0), qh1 = *(const uint4*)(Hb + r1);
        uint4 qm0 = *(const uint4*)(Mb + r0), qm1 = *(const uint4*)(Mb + r1);
        uint4 ql0 = *(const uint4*)(Lb + r0), ql1 = *(const uint4*)(Lb + r1);
        *(uint4*)(lds +              wbyte) = qh0;
        *(uint4*)(lds +  8192      + wbyte) = qm0;
        *(uint4*)(lds + 16384      + wbyte) = ql0;
        *(uint4*)(lds + 24576      + wbyte) = qh1;
        *(uint4*)(lds + 24576+8192 + wbyte) = qm1;
        *(uint4*)(lds + 24576+16384+ wbyte) = ql1;
    }
    __syncthreads();

    // B fragments (query), register-resident for the whole scan
    const int koff = (l >> 4) * 16;
    const int swzR = (l & 7) << 4;
    const int qrow = w * 16 + (l & 15);         // 0..127
    const char* qbuf = lds + ((qrow >> 6) ? 24576 : 0);
    const int qr6 = qrow & 63;
    const int qb0 = (qr6 * 128 + koff) ^ swzR;
    const int qb1 = (qr6 * 128 + 64 + koff) ^ swzR;
    short8 bh0 = *(const short8*)(qbuf + qb0),         bh1 = *(const short8*)(qbuf + qb1);
    short8 bm0 = *(const short8*)(qbuf +  8192 + qb0), bm1 = *(const short8*)(qbuf +  8192 + qb1);
    short8 bl0 = *(const short8*)(qbuf + 16384 + qb0), bl1 = *(const short8*)(qbuf + 16384 + qb1);

    const float sqq   = sqb[i0 + qrow];
    const int   qglob = i0 + qrow;
    const int   crow0 = (l >> 4) * 4;
    const int   dtile = i0 + ((w >> 2) << 6);   // wave-uniform diagonal tile

    __syncthreads();          // all waves finished reading Q

    // stage first candidate tile into buf0
    *(uint4*)(lds +         wbyte) = ph;
    *(uint4*)(lds +  8192 + wbyte) = pm;
    *(uint4*)(lds + 16384 + wbyte) = pl;
    {   // prefetch second tile
        const size_t rb = (size_t)(c0 + 64 + lr) * C + lq * 8;
        ph = *(const uint4*)(Hb + rb);
        pm = *(const uint4*)(Mb + rb);
        pl = *(const uint4*)(Lb + rb);
    }
    __syncthreads();          // first tile visible

    double bd[16];
    #pragma unroll
    for (int k = 0; k < 16; k++) bd[k] = KMAX;

    for (int t = 0; t < 32; t++) {
        const int j0 = c0 + t * 64;
        char* bufA = lds + ((t & 1) ? 24576 : 0);      // compute tile t
        char* bufB = lds + ((t & 1) ? 0 : 24576);      // stage tile t+1

        if (t < 31) {
            *(uint4*)(bufB +         wbyte) = ph;
            *(uint4*)(bufB +  8192 + wbyte) = pm;
            *(uint4*)(bufB + 16384 + wbyte) = pl;
        }
        if (t < 30) {
            const size_t rb = (size_t)(j0 + 128 + lr) * C + lq * 8;
            ph = *(const uint4*)(Hb + rb);
            pm = *(const uint4*)(Mb + rb);
            pl = *(const uint4*)(Lb + rb);
        }

        float4 sqm0 = *(const float4*)(sqb + j0 +      crow0);
        float4 sqm1 = *(const float4*)(sqb + j0 + 16 + crow0);
        float4 sqm2 = *(const float4*)(sqb + j0 + 32 + crow0);
        float4 sqm3 = *(const float4*)(sqb + j0 + 48 + crow0);

        double nk[16];

        #pragma unroll
        for (int m = 0; m < 4; m++) {
            const int arow = m * 16 + (l & 15);
            const int ab0 = (arow * 128 + koff) ^ swzR;
            const int ab1 = (arow * 128 + 64 + koff) ^ swzR;
            short8 ah0 = *(const short8*)(bufA + ab0);
            short8 ah1 = *(const short8*)(bufA + ab1);
            short8 am0 = *(const short8*)(bufA + 8192 + ab0);
            short8 am1 = *(const short8*)(bufA + 8192 + ab1);
            short8 al0 = *(const short8*)(bufA + 16384 + ab0);
            short8 al1 = *(const short8*)(bufA + 16384 + ab1);

            f32x4 acc1 = {0.f, 0.f, 0.f, 0.f};
            acc1 = __builtin_amdgcn_mfma_f32_16x16x32_bf16(am0, bm0, acc1, 0, 0, 0);
            acc1 = __builtin_amdgcn_mfma_f32_16x16x32_bf16(am1, bm1, acc1, 0, 0, 0);
            acc1 = __builtin_amdgcn_mfma_f32_16x16x32_bf16(ah0, bl0, acc1, 0, 0, 0);
            acc1 = __builtin_amdgcn_mfma_f32_16x16x32_bf16(ah1, bl1, acc1, 0, 0, 0);
            acc1 = __builtin_amdgcn_mfma_f32_16x16x32_bf16(al0, bh0, acc1, 0, 0, 0);
            f32x4 acc2 = {0.f, 0.f, 0.f, 0.f};
            acc2 = __builtin_amdgcn_mfma_f32_16x16x32_bf16(al1, bh1, acc2, 0, 0, 0);
            acc2 = __builtin_amdgcn_mfma_f32_16x16x32_bf16(ah0, bm0, acc2, 0, 0, 0);
            acc2 = __builtin_amdgcn_mfma_f32_16x16x32_bf16(ah1, bm1, acc2, 0, 0, 0);
            acc2 = __builtin_amdgcn_mfma_f32_16x16x32_bf16(am0, bh0, acc2, 0, 0, 0);
            acc2 = __builtin_amdgcn_mfma_f32_16x16x32_bf16(am1, bh1, acc2, 0, 0, 0);
            f32x4 acch = {0.f, 0.f, 0.f, 0.f};
            acch = __builtin_amdgcn_mfma_f32_16x16x32_bf16(ah0, bh0, acch, 0, 0, 0);
            acch = __builtin_amdgcn_mfma_f32_16x16x32_bf16(ah1, bh1, acch, 0, 0, 0);

            float4 sqm = (m == 0) ? sqm0 : (m == 1) ? sqm1 : (m == 2) ? sqm2 : sqm3;
            #pragma unroll
            for (int r = 0; r < 4; r++) {
                float sqc = (r == 0) ? sqm.x : (r == 1) ? sqm.y : (r == 2) ? sqm.z : sqm.w;
                float gg = acch[r] + (acc1[r] + acc2[r]);
                float d2 = fmaf(-2.0f, gg, sqq + sqc);
                d2 = fmaxf(d2, 0.0f);
                nk[m * 4 + r] = pack_key(d2, (unsigned)(j0 + m * 16 + crow0 + r));
            }
        }

        // diagonal tile only: kill self-match (wave-uniform branch)
        if (j0 == dtile) {
            #pragma unroll
            for (int m = 0; m < 4; m++)
                #pragma unroll
                for (int r = 0; r < 4; r++)
                    if ((j0 + m * 16 + crow0 + r) == qglob) nk[m * 4 + r] = KMAX;
        }

        // ---- Batcher odd-even mergesort, n=16, DESCENDING (63 comparators) ----
        #pragma unroll
        for (int p = 1; p < 16; p <<= 1) {
            #pragma unroll
            for (int kk = p; kk >= 1; kk >>= 1) {
                #pragma unroll
                for (int j = kk % p; j <= 16 - 1 - kk; j += 2 * kk) {
                    #pragma unroll
                    for (int i = 0; i <= ((kk - 1 < 16 - j - kk - 1) ? kk - 1 : 16 - j - kk - 1); i++) {
                        if ((i + j) / (2 * p) == (i + j + kk) / (2 * p)) {
                            double a = nk[i + j], c2 = nk[i + j + kk];
                            nk[i + j]      = fmax(a, c2);   // descending
                            nk[i + j + kk] = fmin(a, c2);
                        }
                    }
                }
            }
        }
        // ---- lowest-16 of (bd asc ++ nk desc): elementwise min ----
        #pragma unroll
        for (int i = 0; i < 16; i++) bd[i] = fmin(bd[i], nk[i]);
        // ---- bd bitonic -> ascending cleanup (strides 8,4,2,1) ----
        #pragma unroll
        for (int j = 8; j > 0; j >>= 1) {
            #pragma unroll
            for (int i = 0; i < 16; i++) {
                int ixj = i ^ j;
                if (ixj > i) {
                    double a = bd[i], c2 = bd[ixj];
                    bd[i]   = fmin(a, c2);
                    bd[ixj] = fmax(a, c2);
                }
            }
        }

        __syncthreads();       // tile t+1 staged & prior reads done
    }

    // ---- epilogue: two 64-query passes (32KB key scratch each) ----
    uint64_t* keys = (uint64_t*)lds;
    if (w < 4) {               // pass A: queries i0..i0+63
        const int qloc = w * 16 + (l & 15);
        const int base = (qloc * 4 + (l >> 4)) * 16;
        #pragma unroll
        for (int k = 0; k < 16; k++)
            keys[base + k] = __builtin_bit_cast(uint64_t, bd[k]);
    }
    __syncthreads();
    if (tid < 64)
        merge4_store(keys, tid, keysg + ((size_t)b * N + i0 + tid) * 32 + s * 16);
    __syncthreads();
    if (w >= 4) {              // pass B: queries i0+64..i0+127
        const int qloc = (w - 4) * 16 + (l & 15);
        const int base = (qloc * 4 + (l >> 4)) * 16;
        #pragma unroll
        for (int k = 0; k < 16; k++)
            keys[base + k] = __builtin_bit_cast(uint64_t, bd[k]);
    }
    __syncthreads();
    if (tid < 64)
        merge4_store(keys, tid, keysg + ((size_t)b * N + i0 + 64 + tid) * 32 + s * 16);
}

// ---------------------------------------------------------------------------
// Kernel 1b: final 2-way merge of the two halves, one thread per query
// ---------------------------------------------------------------------------
__global__ __launch_bounds__(256)
void knn_merge_kernel(const uint64_t* __restrict__ keysg, int* __restrict__ knn) {
    const int q = blockIdx.x * 256 + threadIdx.x;     // 0..B*N-1
    const uint64_t* A  = keysg + (size_t)q * 32;
    const uint64_t* Bp = A + 16;
    int pa = 0, pb = 0;
    uint64_t ha = A[0], hb = Bp[0];
    int* dst = knn + (size_t)q * K;
    #pragma unroll
    for (int k = 0; k < K; k++) {
        uint64_t mv = ha < hb ? ha : hb;
        dst[k] = (int)(mv & 0xFFFFFFFFu);
        if (mv == ha) { ++pa; ha = (pa < 16) ? A[pa] : ~0ull; }
        else          { ++pb; hb = (pb < 16) ? Bp[pb] : ~0ull; }
    }
}

// ---------------------------------------------------------------------------
// Kernel 2: MFMA MLP (round-8 structure) + fast exact-enough erf gelu.
// A&S 7.1.26: |erf_err| <= 1.5e-7 absolute -> output err ~4e-7 (budget 1.5e-2).
// ---------------------------------------------------------------------------
__device__ __forceinline__ float gelu_fast(float x) {
    float az = fabsf(x) * 0.70710678118654752440f;
    float t  = __builtin_amdgcn_rcpf(fmaf(0.3275911f, az, 1.0f));
    float p  = t * fmaf(t, fmaf(t, fmaf(t, fmaf(t, 1.061405429f, -1.453152027f),
                                        1.421413741f), -0.284496736f), 0.254829592f);
    float e  = p * __builtin_amdgcn_exp2f(-az * az * 1.44269504088896f); // 1-erf(az)
    float g  = 0.5f * x;
    return (x >= 0.0f) ? g * (2.0f - e) : g * e;
}

#define QPW 4

__global__ __launch_bounds__(256)
void mlp_mfma_kernel(const float* __restrict__ F,
                     const unsigned short* __restrict__ HP,
                     const unsigned short* __restrict__ MP,
                     const int* __restrict__ knn,
                     const float* __restrict__ W1, const float* __restrict__ b1,
                     const float* __restrict__ W2, const float* __restrict__ b2,
                     float* __restrict__ out) {
    __shared__ __align__(16) unsigned short W1h[64 * 128];   // 16KB
    __shared__ __align__(16) unsigned short W1m[64 * 128];   // 16KB
    __shared__ __align__(16) unsigned short hbh[4][1024];
    __shared__ __align__(16) unsigned short hbm[4][1024];

    const int tid = threadIdx.x;
    const int l   = tid & 63;
    const int w   = tid >> 6;

    for (int e = tid; e < 8192; e += 256) {
        const int n = e & 63, k = e >> 6;
        const int srcrow = (k < 64) ? (64 + k) : (k - 64);
        float x = W1[srcrow * 64 + n];
        unsigned short hh = f2bf(x);
        unsigned short mm = f2bf(x - bf2f(hh));
        const int byte = (n * 256 + k * 2) ^ ((n & 15) << 4);
        *(unsigned short*)((char*)W1h + byte) = hh;
        *(unsigned short*)((char*)W1m + byte) = mm;
    }

    short8 B2h[4][2], B2m[4][2];
    float b1v[4], b2v[4];
    {
        const int n = (l & 15);
        #pragma unroll
        for (int nt = 0; nt < 4; nt++) {
            const int nn = nt * 16 + n;
            b1v[nt] = b1[nn];
            b2v[nt] = b2[nn];
            #pragma unroll
            for (int c = 0; c < 2; c++) {
                const int k0 = c * 32 + (l >> 4) * 8;
                short8 vh, vm;
                #pragma unroll
                for (int jj = 0; jj < 8; jj++) {
                    float x = W2[(k0 + jj) * 64 + nn];
                    unsigned short hh = f2bf(x);
                    vh[jj] = (short)hh;
                    vm[jj] = (short)f2bf(x - bf2f(hh));
                }
                B2h[nt][c] = vh; B2m[nt][c] = vm;
            }
        }
    }
    __syncthreads();

    const int cb   = (l >> 4) * 8;
    const int swzL = (l & 15) << 4;

    for (int jq = 0; jq < QPW; jq++) {
        const int q  = (blockIdx.x * 4 + w) * QPW + jq;
        const int b  = q >> 12;
        const int ci = q & (N - 1);
        const float*          Fb  = F  + (size_t)b * N * C;
        const unsigned short* HPb = HP + (size_t)b * N * C;
        const unsigned short* MPb = MP + (size_t)b * N * C;

        const int nb = knn[(size_t)q * K + (l & 15)];

        float4 cA0 = *(const float4*)(Fb + (size_t)ci * C + cb);
        float4 cA1 = *(const float4*)(Fb + (size_t)ci * C + cb + 4);
        float4 cB0 = *(const float4*)(Fb + (size_t)ci * C + 32 + cb);
        float4 cB1 = *(const float4*)(Fb + (size_t)ci * C + 36 + cb);
        float4 nA0 = *(const float4*)(Fb + (size_t)nb * C + cb);
        float4 nA1 = *(const float4*)(Fb + (size_t)nb * C + cb + 4);
        float4 nB0 = *(const float4*)(Fb + (size_t)nb * C + 32 + cb);
        float4 nB1 = *(const float4*)(Fb + (size_t)nb * C + 36 + cb);

        short8 ach0 = *(const short8*)(HPb + (size_t)ci * C + cb);
        short8 ach1 = *(const short8*)(HPb + (size_t)ci * C + 32 + cb);
        short8 acm0 = *(const short8*)(MPb + (size_t)ci * C + cb);
        short8 acm1 = *(const short8*)(MPb + (size_t)ci * C + 32 + cb);

        short8 adh0, adm0, adh1, adm1;
        {
            float d0[8] = {nA0.x - cA0.x, nA0.y - cA0.y, nA0.z - cA0.z, nA0.w - cA0.w,
                           nA1.x - cA1.x, nA1.y - cA1.y, nA1.z - cA1.z, nA1.w - cA1.w};
            float d1[8] = {nB0.x - cB0.x, nB0.y - cB0.y, nB0.z - cB0.z, nB0.w - cB0.w,
                           nB1.x - cB1.x, nB1.y - cB1.y, nB1.z - cB1.z, nB1.w - cB1.w};
            #pragma unroll
            for (int jj = 0; jj < 8; jj++) {
                unsigned short h0 = f2bf(d0[jj]);
                adh0[jj] = (short)h0; adm0[jj] = (short)f2bf(d0[jj] - bf2f(h0));
                unsigned short h1 = f2bf(d1[jj]);
                adh1[jj] = (short)h1; adm1[jj] = (short)f2bf(d1[jj] - bf2f(h1));
            }
        }

        #pragma unroll
        for (int nt = 0; nt < 4; nt++) {
            const int rowb = (nt * 16 + (l & 15)) * 256 + (l >> 4) * 16;
            f32x4 a1 = {0.f, 0.f, 0.f, 0.f};
            f32x4 a2 = {0.f, 0.f, 0.f, 0.f};
            #pragma unroll
            for (int kc = 0; kc < 4; kc++) {
                const int byte = (rowb + kc * 64) ^ swzL;
                short8 Bh = *(const short8*)((char*)W1h + byte);
                short8 Bm = *(const short8*)((char*)W1m + byte);
                short8 Ah = (kc == 0) ? adh0 : (kc == 1) ? adh1 : (kc == 2) ? ach0 : ach1;
                short8 Am = (kc == 0) ? adm0 : (kc == 1) ? adm1 : (kc == 2) ? acm0 : acm1;
                a1 = __builtin_amdgcn_mfma_f32_16x16x32_bf16(Ah, Bh, a1, 0, 0, 0);
                a2 = __builtin_amdgcn_mfma_f32_16x16x32_bf16(Ah, Bm, a2, 0, 0, 0);
                a2 = __builtin_amdgcn_mfma_f32_16x16x32_bf16(Am, Bh, a2, 0, 0, 0);
            }
            #pragma unroll
            for (int r = 0; r < 4; r++) {
                const int row = (l >> 4) * 4 + r;
                const int col = nt * 16 + (l & 15);
                float hv = gelu_fast(a1[r] + a2[r] + b1v[nt]);
                unsigned short hh = f2bf(hv);
                unsigned short hm = f2bf(hv - bf2f(hh));
                const int byte = (row * 128 + col * 2) ^ ((row & 7) << 4);
                *(unsigned short*)((char*)&hbh[w][0] + byte) = hh;
                *(unsigned short*)((char*)&hbm[w][0] + byte) = hm;
            }
        }

        asm volatile("s_waitcnt lgkmcnt(0)" ::: "memory");
        __builtin_amdgcn_sched_barrier(0);

        short8 Ah2[2], Am2[2];
        #pragma unroll
        for (int kc = 0; kc < 2; kc++) {
            const int byte = ((l & 15) * 128 + kc * 64 + (l >> 4) * 16) ^ (((l & 15) & 7) << 4);
            Ah2[kc] = *(const short8*)((char*)&hbh[w][0] + byte);
            Am2[kc] = *(const short8*)((char*)&hbm[w][0] + byte);
        }
        #pragma unroll
        for (int nt = 0; nt < 4; nt++) {
            f32x4 a1 = {0.f, 0.f, 0.f, 0.f};
            f32x4 a2 = {0.f, 0.f, 0.f, 0.f};
            #pragma unroll
            for (int kc = 0; kc < 2; kc++) {
                a1 = __builtin_amdgcn_mfma_f32_16x16x32_bf16(Ah2[kc], B2h[nt][kc], a1, 0, 0, 0);
                a2 = __builtin_amdgcn_mfma_f32_16x16x32_bf16(Ah2[kc], B2m[nt][kc], a2, 0, 0, 0);
                a2 = __builtin_amdgcn_mfma_f32_16x16x32_bf16(Am2[kc], B2h[nt][kc], a2, 0, 0, 0);
            }
            float mx = -INFINITY;
            #pragma unroll
            for (int r = 0; r < 4; r++)
                mx = fmaxf(mx, gelu_fast(a1[r] + a2[r] + b2v[nt]));
            mx = fmaxf(mx, __shfl_xor(mx, 16));
            mx = fmaxf(mx, __shfl_xor(mx, 32));
            if (l < 16) out[(size_t)q * D + nt * 16 + l] = mx;
        }
    }
}

// ---------------------------------------------------------------------------
extern "C" void kernel_launch(void* const* d_in, const int* in_sizes, int n_in,
                              void* d_out, int out_size, void* d_ws, size_t ws_size,
                              hipStream_t stream) {
    const float* F  = (const float*)d_in[0];
    const float* W1 = (const float*)d_in[1];
    const float* b1 = (const float*)d_in[2];
    const float* W2 = (const float*)d_in[3];
    const float* b2 = (const float*)d_in[4];
    float* out = (float*)d_out;

    char* ws = (char*)d_ws;
    float*          sq   = (float*)ws;                             // 128 KB
    uint64_t*       keys = (uint64_t*)(ws + (128 << 10));          // 8 MB
    unsigned short* HP   = (unsigned short*)(ws + (8320 << 10));   // 4 MB
    unsigned short* MP   = (unsigned short*)(ws + (12416 << 10));  // 4 MB
    unsigned short* LP   = (unsigned short*)(ws + (16512 << 10));  // 4 MB
    int*            knn  = (int*)LP;   // LP dead after knn_mfma pass (mlp uses HP/MP only)

    prep_kernel<<<dim3(B * N / 256), 256, 0, stream>>>(F, sq, HP, MP, LP);
    knn_mfma_kernel<<<dim3(N / 128, 2, B), 512, 0, stream>>>(HP, MP, LP, sq, keys);
    knn_merge_kernel<<<dim3(B * N / 256), 256, 0, stream>>>(keys, knn);
    mlp_mfma_kernel<<<dim3(B * N / (4 * QPW)), 256, 0, stream>>>(
        F, HP, MP, knn, W1, b1, W2, b2, out);
}